// Round 3
// baseline (10049.809 us; speedup 1.0000x reference)
//
#include <hip/hip_runtime.h>
#include <hip/hip_bf16.h>
#include <math.h>

#define TPB 256
typedef __hip_bfloat16 bf16;

// ---- dtype-adaptive global accessors (bf=1: bf16, bf=0: fp32) -------------
__device__ __forceinline__ float ldI(const void* p, long i, int bf) {
    if (bf) {
        unsigned short h = ((const unsigned short*)p)[i];
        return __uint_as_float(((unsigned int)h) << 16);
    }
    return ((const float*)p)[i];
}
__device__ __forceinline__ void stO(void* p, long i, float v, int bf) {
    if (bf) ((bf16*)p)[i] = __float2bfloat16(v);
    else    ((float*)p)[i] = v;
}
__device__ __forceinline__ float toF(bf16 v) { return __bfloat162float(v); }

// ---- dtype detector: bf16-read of genuine bf16 N(0,1) data is ~100% sane;
//      bf16-read of fp32 data has garbage mantissa halves (~54% sane) -------
__global__ void detect_kernel(const void* __restrict__ x, int* __restrict__ flag) {
    if (threadIdx.x == 0 && blockIdx.x == 0) {
        const unsigned short* u = (const unsigned short*)x;
        int sane = 0;
        for (int i = 0; i < 256; ++i) {
            float v = __uint_as_float(((unsigned int)u[i]) << 16);
            float a = fabsf(v);
            if (a > 0.0009f && a < 1100.f) ++sane;   // NaN compares false
        }
        *flag = (sane >= 224) ? 1 : 0;
    }
}

// ---------------- direct conv2d (zero pad), flag in, fp32 out --------------
template<int CIN, int KH, int KW, int STRIDE, int PAD>
__global__ __launch_bounds__(TPB) void conv2d_kernel(
    const void* __restrict__ x, long xbase, const void* __restrict__ w,
    const void* __restrict__ bia, float* __restrict__ out,
    const int* __restrict__ dflag,
    int N, int Cout, int H, int W, int Wo, int row0, int rows)
{
    int bf = *dflag;
    int idx = blockIdx.x * TPB + threadIdx.x;
    int total = N * Cout * rows * Wo;
    if (idx >= total) return;
    int wo = idx % Wo;
    int t = idx / Wo;
    int r = t % rows; t /= rows;
    int co = t % Cout; int n = t / Cout;
    int ho = row0 + r;
    float acc = ldI(bia, co, bf);
    long wp = (long)co * CIN * KH * KW;
    long xn = xbase + (long)n * CIN * H * W;
    int yb = ho * STRIDE - PAD;
    int xb = wo * STRIDE - PAD;
    for (int ci = 0; ci < CIN; ++ci) {
        long xc = xn + (long)ci * H * W;
        long wc = wp + ci * KH * KW;
        for (int ky = 0; ky < KH; ++ky) {
            int yy = yb + ky;
            if (yy < 0 || yy >= H) continue;
            long rowp = xc + (long)yy * W;
            for (int kx = 0; kx < KW; ++kx) {
                int xx = xb + kx;
                if (xx < 0 || xx >= W) continue;
                acc += ldI(w, wc + ky * KW + kx, bf) * ldI(x, rowp + xx, bf);
            }
        }
    }
    out[idx] = acc;
}

// ---------------- modulated deformable conv --------------------------------
// off layout: [N][3K][bandRows][Wo] fp32 (oy: k, ox: K+k, mask raw: 2K+k)
template<int CIN, int KH, int KW, int STRIDE, int PAD, int TPIX>
__global__ __launch_bounds__(TPB) void deform_kernel(
    const void* __restrict__ x, long xbase, const float* __restrict__ off,
    const void* __restrict__ w, const void* __restrict__ bia,
    void* __restrict__ out, long obase, int outWS,
    const int* __restrict__ dflag,
    int N, int Cout, int H, int W, int Ho, int Wo, int row0, int bandRows)
{
    constexpr int K = KH * KW;
    constexpr int S = CIN * K;
    __shared__ __align__(16) float smp[S * TPIX];
    int bf = *dflag;
    int obf = outWS ? 1 : bf;
    int tilesPerN = (bandRows * Wo) / TPIX;
    int n = blockIdx.x / tilesPerN;
    int lp0 = (blockIdx.x % tilesPerN) * TPIX;
    long xn = xbase + (long)n * CIN * H * W;
    const float* offn = off + (long)n * 3 * K * bandRows * Wo;
    long planeSz = (long)bandRows * Wo;

    for (int e = threadIdx.x; e < S * TPIX; e += TPB) {
        int p = e % TPIX;
        int rest = e / TPIX;
        int k = rest % K;
        int ci = rest / K;
        int lp = lp0 + p;
        int lrow = lp / Wo;
        int wo = lp % Wo;
        int ho = row0 + lrow;
        float oy = offn[(long)k * planeSz + lp];
        float ox = offn[(long)(K + k) * planeSz + lp];
        float mr = offn[(long)(2 * K + k) * planeSz + lp];
        float m = 1.f / (1.f + expf(-mr));
        float py = (float)(ho * STRIDE - PAD + (k / KW)) + oy;
        float px = (float)(wo * STRIDE - PAD + (k % KW)) + ox;
        float y0f = floorf(py), x0f = floorf(px);
        float wy = py - y0f, wx = px - x0f;
        int y0 = (int)y0f, x0 = (int)x0f;
        bool yv0 = (y0 >= 0) && (y0 < H);
        bool yv1 = (y0 + 1 >= 0) && (y0 + 1 < H);
        bool xv0 = (x0 >= 0) && (x0 < W);
        bool xv1 = (x0 + 1 >= 0) && (x0 + 1 < W);
        int y0c = min(max(y0, 0), H - 1);
        int y1c = min(max(y0 + 1, 0), H - 1);
        int x0c = min(max(x0, 0), W - 1);
        int x1c = min(max(x0 + 1, 0), W - 1);
        long xc = xn + (long)ci * H * W;
        float v00 = (yv0 && xv0) ? ldI(x, xc + (long)y0c * W + x0c, bf) : 0.f;
        float v01 = (yv0 && xv1) ? ldI(x, xc + (long)y0c * W + x1c, bf) : 0.f;
        float v10 = (yv1 && xv0) ? ldI(x, xc + (long)y1c * W + x0c, bf) : 0.f;
        float v11 = (yv1 && xv1) ? ldI(x, xc + (long)y1c * W + x1c, bf) : 0.f;
        float val = ((1.f - wy) * ((1.f - wx) * v00 + wx * v01) +
                     wy * ((1.f - wx) * v10 + wx * v11)) * m;
        smp[rest * TPIX + p] = val;
    }
    __syncthreads();

    constexpr int PB = TPIX / 4;
    int slots = Cout * PB;
    for (int o = threadIdx.x; o < slots; o += TPB) {
        int pb = o % PB;
        int co = o / PB;
        long wp = (long)co * S;
        float a0 = 0.f, a1 = 0.f, a2 = 0.f, a3 = 0.f;
        for (int i = 0; i < S; ++i) {
            float wv = ldI(w, wp + i, bf);
            const float4 v = *reinterpret_cast<const float4*>(&smp[i * TPIX + 4 * pb]);
            a0 += wv * v.x; a1 += wv * v.y; a2 += wv * v.z; a3 += wv * v.w;
        }
        float bv = ldI(bia, co, bf);
        int lp = lp0 + 4 * pb;
        int lrow = lp / Wo, wo = lp % Wo;
        int ho = row0 + lrow;
        long op = obase + ((long)(n * Cout + co) * Ho + ho) * Wo + wo;
        stO(out, op + 0, a0 + bv, obf); stO(out, op + 1, a1 + bv, obf);
        stO(out, op + 2, a2 + bv, obf); stO(out, op + 3, a3 + bv, obf);
    }
}

// ---------------- block reduction helper -----------------------------------
__device__ __forceinline__ void reduce2(float& sum, float& sq, float* s1, float* s2)
{
    for (int off = 32; off; off >>= 1) {
        sum += __shfl_down(sum, off, 64);
        sq  += __shfl_down(sq,  off, 64);
    }
    int wid = threadIdx.x >> 6;
    if ((threadIdx.x & 63) == 0) { s1[wid] = sum; s2[wid] = sq; }
    __syncthreads();
    sum = s1[0] + s1[1] + s1[2] + s1[3];
    sq  = s2[0] + s2[1] + s2[2] + s2[3];
}

// ---------------- instance norm (in place), optional relu -------------------
// isWS=1: buffer is bf16 (ws). isWS=0: buffer dtype follows flag (d_out).
__global__ __launch_bounds__(TPB) void instnorm_kernel(
    void* __restrict__ buf, long base0, int isWS, const int* __restrict__ dflag,
    int HW, int relu)
{
    __shared__ float s1[4], s2[4];
    int bf = isWS ? 1 : *dflag;
    long base = base0 + (long)blockIdx.x * HW;
    float sum = 0.f, sq = 0.f;
    for (int i = threadIdx.x; i < HW; i += TPB) {
        float v = ldI(buf, base + i, bf); sum += v; sq += v * v;
    }
    reduce2(sum, sq, s1, s2);
    float mean = sum / HW;
    float var = sq / HW - mean * mean;
    float inv = rsqrtf(var + 1e-5f);
    for (int i = threadIdx.x; i < HW; i += TPB) {
        float v = (ldI(buf, base + i, bf) - mean) * inv;
        if (relu) v = fmaxf(v, 0.f);
        stO(buf, base + i, v, bf);
    }
}

// h += IN(t)   (bf16 ws chain, res-block 1 tail)
__global__ __launch_bounds__(TPB) void instnorm_add_kernel(
    const bf16* __restrict__ t, bf16* __restrict__ h, int HW)
{
    __shared__ float s1[4], s2[4];
    long base = (long)blockIdx.x * HW;
    const bf16* p = t + base;
    bf16* q = h + base;
    float sum = 0.f, sq = 0.f;
    for (int i = threadIdx.x; i < HW; i += TPB) { float v = toF(p[i]); sum += v; sq += v * v; }
    reduce2(sum, sq, s1, s2);
    float mean = sum / HW;
    float inv = rsqrtf(sq / HW - mean * mean + 1e-5f);
    for (int i = threadIdx.x; i < HW; i += TPB)
        q[i] = __float2bfloat16(toF(q[i]) + (toF(p[i]) - mean) * inv);
}

// out = h + IN(t)   (res-block 2 tail, writes d_out per flag)
__global__ __launch_bounds__(TPB) void instnorm_add_out_kernel(
    const bf16* __restrict__ t, const bf16* __restrict__ h,
    void* __restrict__ outp, const int* __restrict__ dflag, int HW)
{
    __shared__ float s1[4], s2[4];
    int bf = *dflag;
    long base = (long)blockIdx.x * HW;
    const bf16* p = t + base;
    const bf16* q = h + base;
    float sum = 0.f, sq = 0.f;
    for (int i = threadIdx.x; i < HW; i += TPB) { float v = toF(p[i]); sum += v; sq += v * v; }
    reduce2(sum, sq, s1, s2);
    float mean = sum / HW;
    float inv = rsqrtf(sq / HW - mean * mean + 1e-5f);
    for (int i = threadIdx.x; i < HW; i += TPB)
        stO(outp, base + i, toF(q[i]) + (toF(p[i]) - mean) * inv, bf);
}

// ---------------- res-block 3x3 conv, reflect pad 1, C=256, 64x64 ----------
__global__ __launch_bounds__(TPB) void resconv_kernel(
    const bf16* __restrict__ x, const void* __restrict__ w,
    const void* __restrict__ bia, bf16* __restrict__ out,
    const int* __restrict__ dflag, int N)
{
    const int C = 256, H = 64, W = 64;
    int bf = *dflag;
    int co = blockIdx.x & 255;
    int n = blockIdx.x >> 8;
    __shared__ float sw[256 * 9];
    for (int i = threadIdx.x; i < C * 9; i += TPB)
        sw[i] = ldI(w, (long)co * C * 9 + i, bf);
    __syncthreads();
    float bias = ldI(bia, co, bf);
    const bf16* xb = x + (long)n * C * H * W;
    for (int q = threadIdx.x; q < 1024; q += TPB) {   // 4-px quads
        int py = q >> 4;
        int xq = (q & 15) << 2;
        int ym1 = py == 0 ? 1 : py - 1;
        int yp1 = py == H - 1 ? H - 2 : py + 1;
        int ys[3] = { ym1, py, yp1 };
        int xi[6];
        #pragma unroll
        for (int j = 0; j < 6; ++j) {
            int xx = xq - 1 + j;
            xi[j] = xx < 0 ? 1 : (xx > W - 1 ? W - 2 : xx);
        }
        float a0 = bias, a1 = bias, a2 = bias, a3 = bias;
        for (int ci = 0; ci < C; ++ci) {
            const bf16* cp = xb + (long)ci * H * W;
            const float* wp = sw + ci * 9;
            #pragma unroll
            for (int a = 0; a < 3; ++a) {
                const bf16* row = cp + ys[a] * W;
                float v0 = toF(row[xi[0]]), v1 = toF(row[xi[1]]), v2 = toF(row[xi[2]]);
                float v3 = toF(row[xi[3]]), v4 = toF(row[xi[4]]), v5 = toF(row[xi[5]]);
                float w0 = wp[a * 3 + 0], w1 = wp[a * 3 + 1], w2 = wp[a * 3 + 2];
                a0 += w0 * v0 + w1 * v1 + w2 * v2;
                a1 += w0 * v1 + w1 * v2 + w2 * v3;
                a2 += w0 * v2 + w1 * v3 + w2 * v4;
                a3 += w0 * v3 + w1 * v4 + w2 * v5;
            }
        }
        bf16* op = out + ((long)(n * 256 + co) * (H * W)) + py * W + xq;
        op[0] = __float2bfloat16(a0); op[1] = __float2bfloat16(a1);
        op[2] = __float2bfloat16(a2); op[3] = __float2bfloat16(a3);
    }
}

// ---------------------------------------------------------------------------
// d_out element offsets: h=[0..2097152), skip1=[2097152..10485760),
//                        skip2=[10485760..14680064)
// ws layout (bytes): [0..16) flag | [16..4194320) h3 bf16 |
//   [4194320..12582928) t1+t2 bf16, aliased by fp32 offb before res blocks
extern "C" void kernel_launch(void* const* d_in, const int* in_sizes, int n_in,
                              void* d_out, int out_size, void* d_ws, size_t ws_size,
                              hipStream_t stream) {
    const void* x      = d_in[0];
    const void* off1_w = d_in[1];  const void* off1_b = d_in[2];
    const void* dcn1_w = d_in[3];  const void* dcn1_b = d_in[4];
    const void* off2_w = d_in[5];  const void* off2_b = d_in[6];
    const void* dcn2_w = d_in[7];  const void* dcn2_b = d_in[8];
    const void* off3_w = d_in[9];  const void* off3_b = d_in[10];
    const void* dcn3_w = d_in[11]; const void* dcn3_b = d_in[12];
    const void* rb1_w1 = d_in[13]; const void* rb1_b1 = d_in[14];
    const void* rb1_w2 = d_in[15]; const void* rb1_b2 = d_in[16];
    const void* rb2_w1 = d_in[17]; const void* rb2_b1 = d_in[18];
    const void* rb2_w2 = d_in[19]; const void* rb2_b2 = d_in[20];

    const long SKIP1 = 2097152;    // elem offsets in d_out
    const long SKIP2 = 10485760;

    int* dflag = (int*)d_ws;
    bf16* wsb  = (bf16*)((char*)d_ws + 16);
    bf16* h3   = wsb;                       // 2,097,152 bf16
    bf16* t1   = wsb + 2097152;             // 2,097,152 bf16
    bf16* t2   = wsb + 4194304;             // 2,097,152 bf16
    float* offb = (float*)(wsb + 2097152);  // aliases t1+t2 (8 MB), dead later

    detect_kernel<<<1, 64, 0, stream>>>(x, dflag);

    // ---- Layer 1: 7x7 s1 p3, Cin=3, K=49, 16 row-bands of 16 ----
    for (int r0 = 0; r0 < 256; r0 += 16) {
        int total = 2 * 147 * 16 * 256;
        conv2d_kernel<3, 7, 7, 1, 3><<<total / TPB, TPB, 0, stream>>>(
            x, 0, off1_w, off1_b, offb, dflag, 2, 147, 256, 256, 256, r0, 16);
        int tiles = 2 * (16 * 256 / 32);
        deform_kernel<3, 7, 7, 1, 3, 32><<<tiles, TPB, 0, stream>>>(
            x, 0, offb, dcn1_w, dcn1_b, d_out, SKIP1, 0, dflag,
            2, 64, 256, 256, 256, 256, r0, 16);
    }
    instnorm_kernel<<<2 * 64, TPB, 0, stream>>>(d_out, SKIP1, 0, dflag, 65536, 1);

    // ---- Layer 2: 4x4 s2 p1, Cin=64, K=16 ----
    {
        int total = 2 * 48 * 128 * 128;
        conv2d_kernel<64, 4, 4, 2, 1><<<total / TPB, TPB, 0, stream>>>(
            d_out, SKIP1, off2_w, off2_b, offb, dflag, 2, 48, 256, 256, 128, 0, 128);
        int tiles = 2 * (128 * 128 / 8);
        deform_kernel<64, 4, 4, 2, 1, 8><<<tiles, TPB, 0, stream>>>(
            d_out, SKIP1, offb, dcn2_w, dcn2_b, d_out, SKIP2, 0, dflag,
            2, 128, 256, 256, 128, 128, 0, 128);
        instnorm_kernel<<<2 * 128, TPB, 0, stream>>>(d_out, SKIP2, 0, dflag, 16384, 1);
    }

    // ---- Layer 3: 4x4 s2 p1, Cin=128, K=16; output bf16 into ws ----
    {
        int total = 2 * 48 * 64 * 64;
        conv2d_kernel<128, 4, 4, 2, 1><<<total / TPB, TPB, 0, stream>>>(
            d_out, SKIP2, off3_w, off3_b, offb, dflag, 2, 48, 128, 128, 64, 0, 64);
        int tiles = 2 * (64 * 64 / 4);
        deform_kernel<128, 4, 4, 2, 1, 4><<<tiles, TPB, 0, stream>>>(
            d_out, SKIP2, offb, dcn3_w, dcn3_b, h3, 0, 1, dflag,
            2, 256, 128, 128, 64, 64, 0, 64);
        instnorm_kernel<<<2 * 256, TPB, 0, stream>>>(h3, 0, 1, dflag, 4096, 1);
    }

    // ---- Res block 1 ---- (offb dead from here)
    resconv_kernel<<<512, TPB, 0, stream>>>(h3, rb1_w1, rb1_b1, t1, dflag, 2);
    instnorm_kernel<<<512, TPB, 0, stream>>>(t1, 0, 1, dflag, 4096, 1);
    resconv_kernel<<<512, TPB, 0, stream>>>(t1, rb1_w2, rb1_b2, t2, dflag, 2);
    instnorm_add_kernel<<<512, TPB, 0, stream>>>(t2, h3, 4096);

    // ---- Res block 2 (final IN+add writes d_out per flag) ----
    resconv_kernel<<<512, TPB, 0, stream>>>(h3, rb2_w1, rb2_b1, t1, dflag, 2);
    instnorm_kernel<<<512, TPB, 0, stream>>>(t1, 0, 1, dflag, 4096, 1);
    resconv_kernel<<<512, TPB, 0, stream>>>(t1, rb2_w2, rb2_b2, t2, dflag, 2);
    instnorm_add_out_kernel<<<512, TPB, 0, stream>>>(t2, h3, d_out, dflag, 4096);
}

// Round 4
// 5379.216 us; speedup vs baseline: 1.8683x; 1.8683x over previous
//
#include <hip/hip_runtime.h>
#include <hip/hip_bf16.h>
#include <math.h>

#define TPB 256
typedef __hip_bfloat16 bf16;

// ---- compile-time dtype accessors (BF=1: bf16, BF=0: fp32) ----------------
template<int BF>
__device__ __forceinline__ float ldT(const void* p, long i) {
    if (BF) {
        unsigned short h = ((const unsigned short*)p)[i];
        return __uint_as_float(((unsigned int)h) << 16);
    }
    return ((const float*)p)[i];
}
template<int BF>
__device__ __forceinline__ void stT(void* p, long i, float v) {
    if (BF) ((bf16*)p)[i] = __float2bfloat16(v);
    else    ((float*)p)[i] = v;
}
__device__ __forceinline__ float toF(bf16 v) { return __bfloat162float(v); }
__device__ __forceinline__ float bitsToF(unsigned short h) {
    return __uint_as_float(((unsigned int)h) << 16);
}

// ---- dtype detector (empirically validated in round 3) --------------------
__global__ void detect_kernel(const void* __restrict__ x, int* __restrict__ flag) {
    if (threadIdx.x == 0 && blockIdx.x == 0) {
        const unsigned short* u = (const unsigned short*)x;
        int sane = 0;
        for (int i = 0; i < 256; ++i) {
            float v = bitsToF(u[i]);
            float a = fabsf(v);
            if (a > 0.0009f && a < 1100.f) ++sane;
        }
        *flag = (sane >= 224) ? 1 : 0;
    }
}

// ===========================================================================
// Patch-GEMM offset conv: stage im2col patches in LDS, broadcast-GEMM.
// out (fp32, band layout [n][COUT][bandRows][Wo]) = w[COUT][S] * patches
// ===========================================================================
template<int BF, int CIN, int KH, int KW, int ST, int PAD, int TPIX, int COUT, int COUTP>
__device__ void offconv_body(const void* __restrict__ x, long xbase,
                             const void* __restrict__ w, const void* __restrict__ bia,
                             float* __restrict__ out, float* smp,
                             int H, int W, int Wo, int row0, int bandRows)
{
    constexpr int K = KH * KW;
    constexpr int S = CIN * K;
    int tilesPerN = (bandRows * Wo) / TPIX;
    int n = blockIdx.x / tilesPerN;
    int lp0 = (blockIdx.x % tilesPerN) * TPIX;
    long xn = xbase + (long)n * CIN * H * W;

    for (int e = threadIdx.x; e < S * TPIX; e += TPB) {
        int p = e % TPIX; int rest = e / TPIX;
        int k = rest % K; int ci = rest / K;
        int lp = lp0 + p;
        int ho = row0 + lp / Wo;
        int wo = lp % Wo;
        int yy = ho * ST - PAD + k / KW;
        int xx = wo * ST - PAD + k % KW;
        float v = 0.f;
        if (yy >= 0 && yy < H && xx >= 0 && xx < W)
            v = ldT<BF>(x, xn + (long)ci * H * W + (long)yy * W + xx);
        smp[rest * TPIX + p] = v;
    }
    __syncthreads();

    constexpr int PXG = (TPIX * COUTP) / TPB;   // pixels per thread
    int co = threadIdx.x % COUTP;               // COUTP mult of 64 -> px group
    int g  = threadIdx.x / COUTP;               //   is wave-uniform (broadcast)
    if (co >= COUT) return;
    int pb = g * PXG;
    float acc[PXG];
    #pragma unroll
    for (int j = 0; j < PXG; ++j) acc[j] = 0.f;
    long wrow = (long)co * S;
    #pragma unroll 4
    for (int i = 0; i < S; ++i) {
        float wv = ldT<BF>(w, wrow + i);
        #pragma unroll
        for (int j = 0; j < PXG; ++j) acc[j] += wv * smp[i * TPIX + pb + j];
    }
    float bv = ldT<BF>(bia, co);
    int lp = lp0 + pb;
    int lrow = lp / Wo, wo = lp % Wo;
    long ob = ((long)(n * COUT + co) * bandRows + lrow) * Wo + wo;
    #pragma unroll
    for (int j = 0; j < PXG; ++j) out[ob + j] = acc[j] + bv;
}

template<int CIN, int KH, int KW, int ST, int PAD, int TPIX, int COUT, int COUTP>
__global__ __launch_bounds__(TPB) void offconv_kernel(
    const void* x, long xbase, const void* w, const void* bia, float* out,
    const int* dflag, int H, int W, int Wo, int row0, int bandRows)
{
    __shared__ __align__(16) float smp[CIN * KH * KW * TPIX];
    if (*dflag)
        offconv_body<1, CIN, KH, KW, ST, PAD, TPIX, COUT, COUTP>(
            x, xbase, w, bia, out, smp, H, W, Wo, row0, bandRows);
    else
        offconv_body<0, CIN, KH, KW, ST, PAD, TPIX, COUT, COUTP>(
            x, xbase, w, bia, out, smp, H, W, Wo, row0, bandRows);
}

// ===========================================================================
// Modulated deformable conv: stage mask*bilinear samples, broadcast-GEMM.
// OUTWS=1 -> out is bf16 ws buffer; OUTWS=0 -> out is d_out (dtype=flag).
// ===========================================================================
template<int BF, int OBF, int CIN, int KH, int KW, int ST, int PAD, int TPIX, int COUT, int COUTP>
__device__ void deform_body(const void* __restrict__ x, long xbase,
                            const float* __restrict__ off,
                            const void* __restrict__ w, const void* __restrict__ bia,
                            void* __restrict__ out, long obase, float* smp,
                            int H, int W, int Ho, int Wo, int row0, int bandRows)
{
    constexpr int K = KH * KW;
    constexpr int S = CIN * K;
    int tilesPerN = (bandRows * Wo) / TPIX;
    int n = blockIdx.x / tilesPerN;
    int lp0 = (blockIdx.x % tilesPerN) * TPIX;
    long xn = xbase + (long)n * CIN * H * W;
    const float* offn = off + (long)n * 3 * K * bandRows * Wo;
    long planeSz = (long)bandRows * Wo;

    for (int e = threadIdx.x; e < S * TPIX; e += TPB) {
        int p = e % TPIX; int rest = e / TPIX;
        int k = rest % K; int ci = rest / K;
        int lp = lp0 + p;
        int lrow = lp / Wo;
        int wo = lp % Wo;
        int ho = row0 + lrow;
        float oy = offn[(long)k * planeSz + lp];
        float ox = offn[(long)(K + k) * planeSz + lp];
        float mr = offn[(long)(2 * K + k) * planeSz + lp];
        float m = 1.f / (1.f + expf(-mr));
        float py = (float)(ho * ST - PAD + (k / KW)) + oy;
        float px = (float)(wo * ST - PAD + (k % KW)) + ox;
        float y0f = floorf(py), x0f = floorf(px);
        float wy = py - y0f, wx = px - x0f;
        int y0 = (int)y0f, x0 = (int)x0f;
        bool yv0 = (y0 >= 0) && (y0 < H);
        bool yv1 = (y0 + 1 >= 0) && (y0 + 1 < H);
        bool xv0 = (x0 >= 0) && (x0 < W);
        bool xv1 = (x0 + 1 >= 0) && (x0 + 1 < W);
        int y0c = min(max(y0, 0), H - 1);
        int y1c = min(max(y0 + 1, 0), H - 1);
        int x0c = min(max(x0, 0), W - 1);
        int x1c = min(max(x0 + 1, 0), W - 1);
        long xc = xn + (long)ci * H * W;
        float v00 = (yv0 && xv0) ? ldT<BF>(x, xc + (long)y0c * W + x0c) : 0.f;
        float v01 = (yv0 && xv1) ? ldT<BF>(x, xc + (long)y0c * W + x1c) : 0.f;
        float v10 = (yv1 && xv0) ? ldT<BF>(x, xc + (long)y1c * W + x0c) : 0.f;
        float v11 = (yv1 && xv1) ? ldT<BF>(x, xc + (long)y1c * W + x1c) : 0.f;
        float val = ((1.f - wy) * ((1.f - wx) * v00 + wx * v01) +
                     wy * ((1.f - wx) * v10 + wx * v11)) * m;
        smp[rest * TPIX + p] = val;
    }
    __syncthreads();

    constexpr int PXG = (TPIX * COUTP) / TPB;
    int co = threadIdx.x % COUTP;
    int g  = threadIdx.x / COUTP;
    if (co >= COUT) return;
    int pb = g * PXG;
    float acc[PXG];
    #pragma unroll
    for (int j = 0; j < PXG; ++j) acc[j] = 0.f;
    long wrow = (long)co * S;
    #pragma unroll 4
    for (int i = 0; i < S; ++i) {
        float wv = ldT<BF>(w, wrow + i);
        #pragma unroll
        for (int j = 0; j < PXG; ++j) acc[j] += wv * smp[i * TPIX + pb + j];
    }
    float bv = ldT<BF>(bia, co);
    int lp = lp0 + pb;
    int lrow = lp / Wo, wo = lp % Wo;
    int ho = row0 + lrow;
    long ob = obase + ((long)(n * COUT + co) * Ho + ho) * Wo + wo;
    #pragma unroll
    for (int j = 0; j < PXG; ++j) stT<OBF>(out, ob + j, acc[j] + bv);
}

template<int OUTWS, int CIN, int KH, int KW, int ST, int PAD, int TPIX, int COUT, int COUTP>
__global__ __launch_bounds__(TPB) void deform_kernel(
    const void* x, long xbase, const float* off, const void* w, const void* bia,
    void* out, long obase, const int* dflag,
    int H, int W, int Ho, int Wo, int row0, int bandRows)
{
    __shared__ __align__(16) float smp[CIN * KH * KW * TPIX];
    if (*dflag)
        deform_body<1, 1, CIN, KH, KW, ST, PAD, TPIX, COUT, COUTP>(
            x, xbase, off, w, bia, out, obase, smp, H, W, Ho, Wo, row0, bandRows);
    else
        deform_body<0, (OUTWS ? 1 : 0), CIN, KH, KW, ST, PAD, TPIX, COUT, COUTP>(
            x, xbase, off, w, bia, out, obase, smp, H, W, Ho, Wo, row0, bandRows);
}

// ===========================================================================
// Res-block 3x3 reflect-pad conv, C=256, 64x64, bf16 ws in/out.
// Block = (n, row, coHalf, pxHalf); thread = (co within half, 16-px segment).
// x rows staged per-64-ci chunk in LDS; LDS reads are wave-uniform broadcast.
// ===========================================================================
template<int BF>
__device__ void resconv_body(const bf16* __restrict__ xin, const void* __restrict__ w,
                             const void* __restrict__ bia, bf16* __restrict__ out,
                             unsigned short* xs)
{
    int b = blockIdx.x;
    int pxH = b & 1, coH = (b >> 1) & 1, r = (b >> 2) & 63, n = b >> 8;
    int t = threadIdx.x;
    int co = (t & 127) + coH * 128;
    int seg = t >> 7;                 // wave-uniform (waves 0,1: seg0; 2,3: seg1)
    int px0 = pxH * 32 + seg * 16;
    int rows[3];
    rows[0] = (r == 0) ? 1 : r - 1;
    rows[1] = r;
    rows[2] = (r == 63) ? 62 : r + 1;
    float acc[16];
    #pragma unroll
    for (int j = 0; j < 16; ++j) acc[j] = 0.f;

    const unsigned short* xraw = (const unsigned short*)xin;
    for (int cc = 0; cc < 4; ++cc) {
        __syncthreads();
        // stage 64 ci x 3 rows x 68 cols (cols -2..65 with reflect)
        for (int e = t; e < 64 * 3 * 68; e += TPB) {
            int col = e % 68; int rr = (e / 68) % 3; int ci = e / 204;
            int c = col - 2;
            c = (c < 0) ? -c : ((c > 63) ? 126 - c : c);
            xs[e] = xraw[((long)(n * 256 + cc * 64 + ci)) * 4096 + rows[rr] * 64 + c];
        }
        __syncthreads();
        for (int ci = 0; ci < 64; ++ci) {
            long wb = ((long)co * 256 + cc * 64 + ci) * 9;
            float w9[9];
            #pragma unroll
            for (int q = 0; q < 9; ++q) w9[q] = ldT<BF>(w, wb + q);
            float X[3][20];
            #pragma unroll
            for (int rr = 0; rr < 3; ++rr) {
                int base = (ci * 3 + rr) * 68 + px0;   // 8B-aligned, broadcast
                #pragma unroll
                for (int q = 0; q < 20; ++q) X[rr][q] = bitsToF(xs[base + q]);
            }
            #pragma unroll
            for (int rr = 0; rr < 3; ++rr)
                #pragma unroll
                for (int dx = 0; dx < 3; ++dx) {
                    float wv = w9[rr * 3 + dx];
                    #pragma unroll
                    for (int j = 0; j < 16; ++j) acc[j] += wv * X[rr][j + dx + 1];
                }
        }
    }
    float bv = ldT<BF>(bia, co);
    long ob = ((long)(n * 256 + co)) * 4096 + r * 64 + px0;
    #pragma unroll
    for (int j = 0; j < 16; ++j) out[ob + j] = __float2bfloat16(acc[j] + bv);
}

__global__ __launch_bounds__(TPB) void resconv_kernel(
    const bf16* xin, const void* w, const void* bia, bf16* out, const int* dflag)
{
    __shared__ __align__(16) unsigned short xs[64 * 3 * 68];
    if (*dflag) resconv_body<1>(xin, w, bia, out, xs);
    else        resconv_body<0>(xin, w, bia, out, xs);
}

// ---------------- block reduction helper -----------------------------------
__device__ __forceinline__ void reduce2(float& sum, float& sq, float* s1, float* s2)
{
    for (int off = 32; off; off >>= 1) {
        sum += __shfl_down(sum, off, 64);
        sq  += __shfl_down(sq,  off, 64);
    }
    int wid = threadIdx.x >> 6;
    if ((threadIdx.x & 63) == 0) { s1[wid] = sum; s2[wid] = sq; }
    __syncthreads();
    sum = s1[0] + s1[1] + s1[2] + s1[3];
    sq  = s2[0] + s2[1] + s2[2] + s2[3];
}

// ---------------- instance norm (in place), optional relu -------------------
__global__ __launch_bounds__(TPB) void instnorm_kernel(
    void* __restrict__ buf, long base0, int isWS, const int* __restrict__ dflag,
    int HW, int relu)
{
    __shared__ float s1[4], s2[4];
    int bf = isWS ? 1 : *dflag;
    long base = base0 + (long)blockIdx.x * HW;
    float sum = 0.f, sq = 0.f;
    for (int i = threadIdx.x; i < HW; i += TPB) {
        float v = bf ? bitsToF(((const unsigned short*)buf)[base + i])
                     : ((const float*)buf)[base + i];
        sum += v; sq += v * v;
    }
    reduce2(sum, sq, s1, s2);
    float mean = sum / HW;
    float inv = rsqrtf(sq / HW - mean * mean + 1e-5f);
    for (int i = threadIdx.x; i < HW; i += TPB) {
        float v = bf ? bitsToF(((const unsigned short*)buf)[base + i])
                     : ((const float*)buf)[base + i];
        v = (v - mean) * inv;
        if (relu) v = fmaxf(v, 0.f);
        if (bf) ((bf16*)buf)[base + i] = __float2bfloat16(v);
        else    ((float*)buf)[base + i] = v;
    }
}

// h += IN(t)   (bf16 ws chain, res-block 1 tail)
__global__ __launch_bounds__(TPB) void instnorm_add_kernel(
    const bf16* __restrict__ t, bf16* __restrict__ h, int HW)
{
    __shared__ float s1[4], s2[4];
    long base = (long)blockIdx.x * HW;
    const bf16* p = t + base;
    bf16* q = h + base;
    float sum = 0.f, sq = 0.f;
    for (int i = threadIdx.x; i < HW; i += TPB) { float v = toF(p[i]); sum += v; sq += v * v; }
    reduce2(sum, sq, s1, s2);
    float mean = sum / HW;
    float inv = rsqrtf(sq / HW - mean * mean + 1e-5f);
    for (int i = threadIdx.x; i < HW; i += TPB)
        q[i] = __float2bfloat16(toF(q[i]) + (toF(p[i]) - mean) * inv);
}

// out = h + IN(t)   (res-block 2 tail, writes d_out per flag)
__global__ __launch_bounds__(TPB) void instnorm_add_out_kernel(
    const bf16* __restrict__ t, const bf16* __restrict__ h,
    void* __restrict__ outp, const int* __restrict__ dflag, int HW)
{
    __shared__ float s1[4], s2[4];
    int bf = *dflag;
    long base = (long)blockIdx.x * HW;
    const bf16* p = t + base;
    const bf16* q = h + base;
    float sum = 0.f, sq = 0.f;
    for (int i = threadIdx.x; i < HW; i += TPB) { float v = toF(p[i]); sum += v; sq += v * v; }
    reduce2(sum, sq, s1, s2);
    float mean = sum / HW;
    float inv = rsqrtf(sq / HW - mean * mean + 1e-5f);
    for (int i = threadIdx.x; i < HW; i += TPB) {
        float v = toF(q[i]) + (toF(p[i]) - mean) * inv;
        if (bf) ((bf16*)outp)[base + i] = __float2bfloat16(v);
        else    ((float*)outp)[base + i] = v;
    }
}

// ---------------------------------------------------------------------------
// d_out element offsets: h=[0..2097152), skip1=[2097152..10485760),
//                        skip2=[10485760..14680064)
// ws layout (bytes): [0..16) flag | [16..4194320) h3 bf16 |
//   [4194320..12582928) t1+t2 bf16, aliased by fp32 offb before res blocks
extern "C" void kernel_launch(void* const* d_in, const int* in_sizes, int n_in,
                              void* d_out, int out_size, void* d_ws, size_t ws_size,
                              hipStream_t stream) {
    const void* x      = d_in[0];
    const void* off1_w = d_in[1];  const void* off1_b = d_in[2];
    const void* dcn1_w = d_in[3];  const void* dcn1_b = d_in[4];
    const void* off2_w = d_in[5];  const void* off2_b = d_in[6];
    const void* dcn2_w = d_in[7];  const void* dcn2_b = d_in[8];
    const void* off3_w = d_in[9];  const void* off3_b = d_in[10];
    const void* dcn3_w = d_in[11]; const void* dcn3_b = d_in[12];
    const void* rb1_w1 = d_in[13]; const void* rb1_b1 = d_in[14];
    const void* rb1_w2 = d_in[15]; const void* rb1_b2 = d_in[16];
    const void* rb2_w1 = d_in[17]; const void* rb2_b1 = d_in[18];
    const void* rb2_w2 = d_in[19]; const void* rb2_b2 = d_in[20];

    const long SKIP1 = 2097152;
    const long SKIP2 = 10485760;

    int* dflag = (int*)d_ws;
    bf16* wsb  = (bf16*)((char*)d_ws + 16);
    bf16* h3   = wsb;                       // 2,097,152 bf16
    bf16* t1   = wsb + 2097152;             // 2,097,152 bf16
    bf16* t2   = wsb + 4194304;             // 2,097,152 bf16
    float* offb = (float*)(wsb + 2097152);  // aliases t1+t2 (8 MB), dead later

    detect_kernel<<<1, 64, 0, stream>>>(x, dflag);

    // ---- Layer 1: 7x7 s1 p3, Cin=3, K=49, 16 row-bands of 16 rows ----
    for (int r0 = 0; r0 < 256; r0 += 16) {
        offconv_kernel<3, 7, 7, 1, 3, 32, 147, 256><<<256, TPB, 0, stream>>>(
            x, 0, off1_w, off1_b, offb, dflag, 256, 256, 256, r0, 16);
        deform_kernel<0, 3, 7, 7, 1, 3, 32, 64, 64><<<256, TPB, 0, stream>>>(
            x, 0, offb, dcn1_w, dcn1_b, d_out, SKIP1, dflag,
            256, 256, 256, 256, r0, 16);
    }
    instnorm_kernel<<<2 * 64, TPB, 0, stream>>>(d_out, SKIP1, 0, dflag, 65536, 1);

    // ---- Layer 2: 4x4 s2 p1, Cin=64, K=16 ----
    offconv_kernel<64, 4, 4, 2, 1, 8, 48, 64><<<4096, TPB, 0, stream>>>(
        d_out, SKIP1, off2_w, off2_b, offb, dflag, 256, 256, 128, 0, 128);
    deform_kernel<0, 64, 4, 4, 2, 1, 8, 128, 128><<<4096, TPB, 0, stream>>>(
        d_out, SKIP1, offb, dcn2_w, dcn2_b, d_out, SKIP2, dflag,
        256, 256, 128, 128, 0, 128);
    instnorm_kernel<<<2 * 128, TPB, 0, stream>>>(d_out, SKIP2, 0, dflag, 16384, 1);

    // ---- Layer 3: 4x4 s2 p1, Cin=128, K=16; output bf16 into ws ----
    offconv_kernel<128, 4, 4, 2, 1, 4, 48, 64><<<2048, TPB, 0, stream>>>(
        d_out, SKIP2, off3_w, off3_b, offb, dflag, 128, 128, 64, 0, 64);
    deform_kernel<1, 128, 4, 4, 2, 1, 4, 256, 256><<<2048, TPB, 0, stream>>>(
        d_out, SKIP2, offb, dcn3_w, dcn3_b, h3, 0, dflag,
        128, 128, 64, 64, 0, 64);
    instnorm_kernel<<<2 * 256, TPB, 0, stream>>>(h3, 0, 1, dflag, 4096, 1);

    // ---- Res block 1 ---- (offb dead from here)
    resconv_kernel<<<512, TPB, 0, stream>>>(h3, rb1_w1, rb1_b1, t1, dflag);
    instnorm_kernel<<<512, TPB, 0, stream>>>(t1, 0, 1, dflag, 4096, 1);
    resconv_kernel<<<512, TPB, 0, stream>>>(t1, rb1_w2, rb1_b2, t2, dflag);
    instnorm_add_kernel<<<512, TPB, 0, stream>>>(t2, h3, 4096);

    // ---- Res block 2 (final IN+add writes d_out per flag) ----
    resconv_kernel<<<512, TPB, 0, stream>>>(h3, rb2_w1, rb2_b1, t1, dflag);
    instnorm_kernel<<<512, TPB, 0, stream>>>(t1, 0, 1, dflag, 4096, 1);
    resconv_kernel<<<512, TPB, 0, stream>>>(t1, rb2_w2, rb2_b2, t2, dflag);
    instnorm_add_out_kernel<<<512, TPB, 0, stream>>>(t2, h3, d_out, dflag, 4096);
}

// Round 5
// 4004.345 us; speedup vs baseline: 2.5097x; 1.3433x over previous
//
#include <hip/hip_runtime.h>
#include <hip/hip_bf16.h>
#include <math.h>

#define TPB 256
typedef __hip_bfloat16 bf16;

// ---- compile-time dtype accessors (BF=1: bf16, BF=0: fp32) ----------------
template<int BF>
__device__ __forceinline__ float ldT(const void* p, long i) {
    if (BF) {
        unsigned short h = ((const unsigned short*)p)[i];
        return __uint_as_float(((unsigned int)h) << 16);
    }
    return ((const float*)p)[i];
}
template<int BF>
__device__ __forceinline__ void stT(void* p, long i, float v) {
    if (BF) ((bf16*)p)[i] = __float2bfloat16(v);
    else    ((float*)p)[i] = v;
}
__device__ __forceinline__ float toF(bf16 v) { return __bfloat162float(v); }
__device__ __forceinline__ float bitsToF(unsigned short h) {
    return __uint_as_float(((unsigned int)h) << 16);
}

// ---- dtype detector (validated round 3/4) ---------------------------------
__global__ void detect_kernel(const void* __restrict__ x, int* __restrict__ flag) {
    if (threadIdx.x == 0 && blockIdx.x == 0) {
        const unsigned short* u = (const unsigned short*)x;
        int sane = 0;
        for (int i = 0; i < 256; ++i) {
            float v = bitsToF(u[i]);
            float a = fabsf(v);
            if (a > 0.0009f && a < 1100.f) ++sane;
        }
        *flag = (sane >= 224) ? 1 : 0;
    }
}

// ---- weight repack: w[Cout][S] (flag dtype) -> wT[S][Cout] fp32 -----------
template<int BF>
__device__ void repack_body(const void* __restrict__ w, float* __restrict__ out,
                            int Cout, int S) {
    int total = Cout * S;
    for (int idx = blockIdx.x * TPB + threadIdx.x; idx < total; idx += gridDim.x * TPB) {
        int co = idx / S, i = idx - co * S;
        out[(long)i * Cout + co] = ldT<BF>(w, idx);
    }
}
__global__ __launch_bounds__(TPB) void repack_kernel(
    const void* w, float* out, const int* dflag, int Cout, int S) {
    if (*dflag) repack_body<1>(w, out, Cout, S);
    else        repack_body<0>(w, out, Cout, S);
}

// ---- bias pack: 10 vectors -> one fp32 array ------------------------------
template<int BF>
__device__ void biaspack_body(const void* const* ps, const int* ls, float* out) {
    int off = 0;
    for (int v = 0; v < 10; ++v) {
        for (int i = threadIdx.x; i < ls[v]; i += TPB) out[off + i] = ldT<BF>(ps[v], i);
        off += ls[v];
    }
}
__global__ __launch_bounds__(TPB) void biaspack_kernel(
    const void* b0, const void* b1, const void* b2, const void* b3, const void* b4,
    const void* b5, const void* b6, const void* b7, const void* b8, const void* b9,
    float* out, const int* dflag) {
    const void* ps[10] = {b0,b1,b2,b3,b4,b5,b6,b7,b8,b9};
    int ls[10] = {147,64,48,128,48,256,256,256,256,256};
    if (*dflag) biaspack_body<1>(ps, ls, out);
    else        biaspack_body<0>(ps, ls, out);
}

// ===========================================================================
// Fused layer 1: offset conv (147ch, 7x7, Cin=3) + deformable conv (64ch)
// One block = 32 consecutive pixels of one output row.
// ===========================================================================
template<int BF>
__device__ void layer1_body(const void* __restrict__ x, const float* __restrict__ wt1,
                            const float* __restrict__ wt2, const float* __restrict__ bias1,
                            const float* __restrict__ bias2, void* __restrict__ out,
                            long obase, float* xs, float* offs, float* smp)
{
    int b = blockIdx.x;
    int n = b >> 11;                // 2048 tiles per image
    int rt = b & 2047;
    int ho = rt >> 3;
    int wo0 = (rt & 7) << 5;
    long xn = (long)n * 3 * 65536;
    int t = threadIdx.x;

    // stage x patch: 3 ci x 7 rows x 38 cols (store stride 40), zero-pad
    for (int e = t; e < 3 * 7 * 40; e += TPB) {
        int cc = e % 40; int rr = (e / 40) % 7; int ci = e / 280;
        int yy = ho - 3 + rr; int xx = wo0 - 3 + cc;
        float v = 0.f;
        if (cc < 38 && yy >= 0 && yy < 256 && xx >= 0 && xx < 256)
            v = ldT<BF>(x, xn + (long)ci * 65536 + yy * 256 + xx);
        xs[e] = v;
    }
    __syncthreads();

    // offset conv: 147 channels x 32 px
    for (int e = t; e < 147 * 32; e += TPB) {
        int ch = e >> 5, p = e & 31;
        float acc = bias1[ch];
        int i = 0;
        for (int ci = 0; ci < 3; ++ci)
            for (int ky = 0; ky < 7; ++ky) {
                const float* xr = xs + (ci * 7 + ky) * 40 + p;
                #pragma unroll
                for (int kx = 0; kx < 7; ++kx, ++i)
                    acc += wt1[i * 147 + ch] * xr[kx];
            }
        offs[e] = acc;
    }
    __syncthreads();

    // bilinear sampling with sigmoid mask: 147 (ci,k) rows x 32 px
    for (int e = t; e < 147 * 32; e += TPB) {
        int p = e & 31; int rest = e >> 5;
        int k = rest % 49; int ci = rest / 49;
        float oy = offs[k * 32 + p];
        float ox = offs[(49 + k) * 32 + p];
        float mr = offs[(98 + k) * 32 + p];
        float m = 1.f / (1.f + expf(-mr));
        float py = (float)(ho - 3 + k / 7) + oy;
        float px = (float)(wo0 + p - 3 + k % 7) + ox;
        float y0f = floorf(py), x0f = floorf(px);
        float wy = py - y0f, wx = px - x0f;
        int y0 = (int)y0f, x0 = (int)x0f;
        bool yv0 = (y0 >= 0) && (y0 < 256);
        bool yv1 = (y0 + 1 >= 0) && (y0 + 1 < 256);
        bool xv0 = (x0 >= 0) && (x0 < 256);
        bool xv1 = (x0 + 1 >= 0) && (x0 + 1 < 256);
        int y0c = min(max(y0, 0), 255), y1c = min(max(y0 + 1, 0), 255);
        int x0c = min(max(x0, 0), 255), x1c = min(max(x0 + 1, 0), 255);
        long xc = xn + (long)ci * 65536;
        float v00 = (yv0 && xv0) ? ldT<BF>(x, xc + y0c * 256 + x0c) : 0.f;
        float v01 = (yv0 && xv1) ? ldT<BF>(x, xc + y0c * 256 + x1c) : 0.f;
        float v10 = (yv1 && xv0) ? ldT<BF>(x, xc + y1c * 256 + x0c) : 0.f;
        float v11 = (yv1 && xv1) ? ldT<BF>(x, xc + y1c * 256 + x1c) : 0.f;
        float val = ((1.f - wy) * ((1.f - wx) * v00 + wx * v01) +
                     wy * ((1.f - wx) * v10 + wx * v11)) * m;
        smp[e] = val;
    }
    __syncthreads();

    // GEMM: 64 cout x 147 k x 32 px; thread = (co, 8-px group)
    int co = t & 63, g = t >> 6;
    int pb = g * 8;
    float acc[8];
    #pragma unroll
    for (int j = 0; j < 8; ++j) acc[j] = 0.f;
    #pragma unroll 4
    for (int i = 0; i < 147; ++i) {
        float wv = wt2[i * 64 + co];
        const float4 a = *(const float4*)&smp[i * 32 + pb];
        const float4 c = *(const float4*)&smp[i * 32 + pb + 4];
        acc[0] += wv * a.x; acc[1] += wv * a.y; acc[2] += wv * a.z; acc[3] += wv * a.w;
        acc[4] += wv * c.x; acc[5] += wv * c.y; acc[6] += wv * c.z; acc[7] += wv * c.w;
    }
    float bv = bias2[co];
    long ob = obase + ((long)(n * 64 + co) * 256 + ho) * 256 + wo0 + pb;
    #pragma unroll
    for (int j = 0; j < 8; ++j) stT<BF>(out, ob + j, acc[j] + bv);
}

__global__ __launch_bounds__(TPB) void layer1_kernel(
    const void* x, const float* wt1, const float* wt2,
    const float* bias1, const float* bias2, void* out, long obase, const int* dflag)
{
    __shared__ __align__(16) float xs[3 * 7 * 40];
    __shared__ __align__(16) float offs[147 * 32];
    __shared__ __align__(16) float smp[147 * 32];
    if (*dflag) layer1_body<1>(x, wt1, wt2, bias1, bias2, out, obase, xs, offs, smp);
    else        layer1_body<0>(x, wt1, wt2, bias1, bias2, out, obase, xs, offs, smp);
}

// ===========================================================================
// Offset conv for layers 2/3 (im2col patch-GEMM, transposed fp32 weights)
// ===========================================================================
template<int BF, int CIN, int KH, int KW, int ST, int PAD, int TPIX, int COUT, int COUTP>
__device__ void offconv_body(const void* __restrict__ x, long xbase,
                             const float* __restrict__ wt, const float* __restrict__ bias_f,
                             float* __restrict__ out, float* smp, int H, int W, int Ho, int Wo)
{
    constexpr int K = KH * KW, S = CIN * K;
    int tilesPerN = (Ho * Wo) / TPIX;
    int n = blockIdx.x / tilesPerN;
    int lp0 = (blockIdx.x % tilesPerN) * TPIX;
    long xn = xbase + (long)n * CIN * H * W;
    for (int e = threadIdx.x; e < S * TPIX; e += TPB) {
        int p = e % TPIX; int rest = e / TPIX;
        int k = rest % K; int ci = rest / K;
        int lp = lp0 + p;
        int ho = lp / Wo, wo = lp % Wo;
        int yy = ho * ST - PAD + k / KW;
        int xx = wo * ST - PAD + k % KW;
        float v = 0.f;
        if (yy >= 0 && yy < H && xx >= 0 && xx < W)
            v = ldT<BF>(x, xn + (long)ci * H * W + (long)yy * W + xx);
        smp[rest * TPIX + p] = v;
    }
    __syncthreads();
    constexpr int PXG = (TPIX * COUTP) / TPB;
    int co = threadIdx.x % COUTP;
    int g  = threadIdx.x / COUTP;
    if (co >= COUT) return;
    int pb = g * PXG;
    float acc[PXG];
    #pragma unroll
    for (int j = 0; j < PXG; ++j) acc[j] = 0.f;
    #pragma unroll 8
    for (int i = 0; i < S; ++i) {
        float wv = wt[(long)i * COUT + co];
        #pragma unroll
        for (int j = 0; j < PXG; ++j) acc[j] += wv * smp[i * TPIX + pb + j];
    }
    float bv = bias_f[co];
    int lp = lp0 + pb;
    int lr = lp / Wo, wo = lp % Wo;
    long ob = ((long)(n * COUT + co) * Ho + lr) * Wo + wo;
    #pragma unroll
    for (int j = 0; j < PXG; ++j) out[ob + j] = acc[j] + bv;
}

template<int CIN, int KH, int KW, int ST, int PAD, int TPIX, int COUT, int COUTP>
__global__ __launch_bounds__(TPB) void offconv_kernel(
    const void* x, long xbase, const float* wt, const float* bias_f, float* out,
    const int* dflag, int H, int W, int Ho, int Wo)
{
    __shared__ __align__(16) float smp[CIN * KH * KW * TPIX];
    if (*dflag)
        offconv_body<1, CIN, KH, KW, ST, PAD, TPIX, COUT, COUTP>(
            x, xbase, wt, bias_f, out, smp, H, W, Ho, Wo);
    else
        offconv_body<0, CIN, KH, KW, ST, PAD, TPIX, COUT, COUTP>(
            x, xbase, wt, bias_f, out, smp, H, W, Ho, Wo);
}

// ===========================================================================
// Deformable conv layers 2/3 (transposed fp32 weights, PXG=4 float4 GEMM)
// ===========================================================================
template<int BF, int OBF, int CIN, int KH, int KW, int ST, int PAD, int TPIX, int COUT, int COUTP>
__device__ void deform_body(const void* __restrict__ x, long xbase,
                            const float* __restrict__ off, const float* __restrict__ wt,
                            const float* __restrict__ bias_f, void* __restrict__ out,
                            long obase, float* smp, int H, int W, int Ho, int Wo)
{
    constexpr int K = KH * KW, S = CIN * K;
    int tilesPerN = (Ho * Wo) / TPIX;
    int n = blockIdx.x / tilesPerN;
    int lp0 = (blockIdx.x % tilesPerN) * TPIX;
    long xn = xbase + (long)n * CIN * H * W;
    const float* offn = off + (long)n * 3 * K * Ho * Wo;
    long planeSz = (long)Ho * Wo;

    for (int e = threadIdx.x; e < S * TPIX; e += TPB) {
        int p = e % TPIX; int rest = e / TPIX;
        int k = rest % K; int ci = rest / K;
        int lp = lp0 + p;
        int ho = lp / Wo, wo = lp % Wo;
        float oy = offn[(long)k * planeSz + lp];
        float ox = offn[(long)(K + k) * planeSz + lp];
        float mr = offn[(long)(2 * K + k) * planeSz + lp];
        float m = 1.f / (1.f + expf(-mr));
        float py = (float)(ho * ST - PAD + (k / KW)) + oy;
        float px = (float)(wo * ST - PAD + (k % KW)) + ox;
        float y0f = floorf(py), x0f = floorf(px);
        float wy = py - y0f, wx = px - x0f;
        int y0 = (int)y0f, x0 = (int)x0f;
        bool yv0 = (y0 >= 0) && (y0 < H);
        bool yv1 = (y0 + 1 >= 0) && (y0 + 1 < H);
        bool xv0 = (x0 >= 0) && (x0 < W);
        bool xv1 = (x0 + 1 >= 0) && (x0 + 1 < W);
        int y0c = min(max(y0, 0), H - 1), y1c = min(max(y0 + 1, 0), H - 1);
        int x0c = min(max(x0, 0), W - 1), x1c = min(max(x0 + 1, 0), W - 1);
        long xc = xn + (long)ci * H * W;
        float v00 = (yv0 && xv0) ? ldT<BF>(x, xc + (long)y0c * W + x0c) : 0.f;
        float v01 = (yv0 && xv1) ? ldT<BF>(x, xc + (long)y0c * W + x1c) : 0.f;
        float v10 = (yv1 && xv0) ? ldT<BF>(x, xc + (long)y1c * W + x0c) : 0.f;
        float v11 = (yv1 && xv1) ? ldT<BF>(x, xc + (long)y1c * W + x1c) : 0.f;
        float val = ((1.f - wy) * ((1.f - wx) * v00 + wx * v01) +
                     wy * ((1.f - wx) * v10 + wx * v11)) * m;
        smp[rest * TPIX + p] = val;
    }
    __syncthreads();

    constexpr int PXG = (TPIX * COUTP) / TPB;
    static_assert(PXG == 4, "deform GEMM assumes PXG==4");
    int co = threadIdx.x % COUTP;
    int g  = threadIdx.x / COUTP;
    int pb = g * PXG;
    float a0 = 0.f, a1 = 0.f, a2 = 0.f, a3 = 0.f;
    #pragma unroll 8
    for (int i = 0; i < S; ++i) {
        float wv = wt[(long)i * COUT + co];
        const float4 v = *(const float4*)&smp[i * TPIX + pb];
        a0 += wv * v.x; a1 += wv * v.y; a2 += wv * v.z; a3 += wv * v.w;
    }
    float bv = bias_f[co];
    int lp = lp0 + pb;
    int lr = lp / Wo, wo = lp % Wo;
    long ob = obase + ((long)(n * COUT + co) * Ho + lr) * Wo + wo;
    stT<OBF>(out, ob + 0, a0 + bv); stT<OBF>(out, ob + 1, a1 + bv);
    stT<OBF>(out, ob + 2, a2 + bv); stT<OBF>(out, ob + 3, a3 + bv);
}

template<int OUTWS, int CIN, int KH, int KW, int ST, int PAD, int TPIX, int COUT, int COUTP>
__global__ __launch_bounds__(TPB) void deform_kernel(
    const void* x, long xbase, const float* off, const float* wt, const float* bias_f,
    void* out, long obase, const int* dflag, int H, int W, int Ho, int Wo)
{
    __shared__ __align__(16) float smp[CIN * KH * KW * TPIX];
    if (*dflag)
        deform_body<1, 1, CIN, KH, KW, ST, PAD, TPIX, COUT, COUTP>(
            x, xbase, off, wt, bias_f, out, obase, smp, H, W, Ho, Wo);
    else
        deform_body<0, (OUTWS ? 1 : 0), CIN, KH, KW, ST, PAD, TPIX, COUT, COUTP>(
            x, xbase, off, wt, bias_f, out, obase, smp, H, W, Ho, Wo);
}

// ===========================================================================
// Res-block 3x3 reflect-pad conv, C=256, 64x64, bf16 in/out, fp32 wT (coalesced)
// ===========================================================================
__global__ __launch_bounds__(TPB) void resconv_kernel(
    const bf16* __restrict__ xin, const float* __restrict__ wt,
    const float* __restrict__ bias_f, bf16* __restrict__ out)
{
    __shared__ __align__(16) float xs[32 * 3 * 72];
    int b = blockIdx.x;
    int pxH = b & 1, coH = (b >> 1) & 1, r = (b >> 2) & 63, n = b >> 8;
    int t = threadIdx.x;
    int co = (t & 127) + coH * 128;
    int seg = t >> 7;                         // wave-uniform
    int px0 = pxH * 32 + seg * 16;
    int rows[3];
    rows[0] = (r == 0) ? 1 : r - 1;
    rows[1] = r;
    rows[2] = (r == 63) ? 62 : r + 1;
    float acc[16];
    #pragma unroll
    for (int j = 0; j < 16; ++j) acc[j] = 0.f;
    const unsigned short* xraw = (const unsigned short*)xin;

    for (int cc = 0; cc < 8; ++cc) {
        __syncthreads();
        for (int e = t; e < 32 * 3 * 72; e += TPB) {
            int col = e % 72; int rr = (e / 72) % 3; int ci = e / 216;
            int c = col - 2;
            c = (c < 0) ? -c : ((c > 63) ? 126 - c : c);
            xs[e] = bitsToF(xraw[((long)(n * 256 + cc * 32 + ci)) * 4096 + rows[rr] * 64 + c]);
        }
        __syncthreads();
        for (int ci = 0; ci < 32; ++ci) {
            int cig = cc * 32 + ci;
            float w9[9];
            #pragma unroll
            for (int q = 0; q < 9; ++q) w9[q] = wt[((long)cig * 9 + q) * 256 + co];
            float X[3][20];
            #pragma unroll
            for (int rr = 0; rr < 3; ++rr) {
                int base = (ci * 3 + rr) * 72 + px0;   // 16B-aligned, broadcast
                #pragma unroll
                for (int q = 0; q < 20; ++q) X[rr][q] = xs[base + q];
            }
            #pragma unroll
            for (int rr = 0; rr < 3; ++rr)
                #pragma unroll
                for (int dx = 0; dx < 3; ++dx) {
                    float wv = w9[rr * 3 + dx];
                    #pragma unroll
                    for (int j = 0; j < 16; ++j) acc[j] += wv * X[rr][j + dx + 1];
                }
        }
    }
    float bv = bias_f[co];
    long ob = ((long)(n * 256 + co)) * 4096 + r * 64 + px0;
    #pragma unroll
    for (int j = 0; j < 16; ++j) out[ob + j] = __float2bfloat16(acc[j] + bv);
}

// ---------------- block reduction (up to 16 waves) -------------------------
__device__ __forceinline__ void reduce2(float& sum, float& sq, float* s1, float* s2)
{
    for (int off = 32; off; off >>= 1) {
        sum += __shfl_down(sum, off, 64);
        sq  += __shfl_down(sq,  off, 64);
    }
    int nw = blockDim.x >> 6;
    int wid = threadIdx.x >> 6;
    if ((threadIdx.x & 63) == 0) { s1[wid] = sum; s2[wid] = sq; }
    __syncthreads();
    sum = 0.f; sq = 0.f;
    for (int w = 0; w < nw; ++w) { sum += s1[w]; sq += s2[w]; }
}

// ---------------- instance norm (in place), optional relu ------------------
__global__ void instnorm_kernel(
    void* __restrict__ buf, long base0, int isWS, const int* __restrict__ dflag,
    int HW, int relu)
{
    __shared__ float s1[16], s2[16];
    int bf = isWS ? 1 : *dflag;
    long base = base0 + (long)blockIdx.x * HW;
    float sum = 0.f, sq = 0.f;
    for (int i = threadIdx.x; i < HW; i += blockDim.x) {
        float v = bf ? bitsToF(((const unsigned short*)buf)[base + i])
                     : ((const float*)buf)[base + i];
        sum += v; sq += v * v;
    }
    reduce2(sum, sq, s1, s2);
    float mean = sum / HW;
    float inv = rsqrtf(sq / HW - mean * mean + 1e-5f);
    for (int i = threadIdx.x; i < HW; i += blockDim.x) {
        float v = bf ? bitsToF(((const unsigned short*)buf)[base + i])
                     : ((const float*)buf)[base + i];
        v = (v - mean) * inv;
        if (relu) v = fmaxf(v, 0.f);
        if (bf) ((bf16*)buf)[base + i] = __float2bfloat16(v);
        else    ((float*)buf)[base + i] = v;
    }
}

// h += IN(t)   (bf16 ws chain, res-block 1 tail)
__global__ __launch_bounds__(TPB) void instnorm_add_kernel(
    const bf16* __restrict__ t, bf16* __restrict__ h, int HW)
{
    __shared__ float s1[16], s2[16];
    long base = (long)blockIdx.x * HW;
    const bf16* p = t + base;
    bf16* q = h + base;
    float sum = 0.f, sq = 0.f;
    for (int i = threadIdx.x; i < HW; i += TPB) { float v = toF(p[i]); sum += v; sq += v * v; }
    reduce2(sum, sq, s1, s2);
    float mean = sum / HW;
    float inv = rsqrtf(sq / HW - mean * mean + 1e-5f);
    for (int i = threadIdx.x; i < HW; i += TPB)
        q[i] = __float2bfloat16(toF(q[i]) + (toF(p[i]) - mean) * inv);
}

// out = h + IN(t)   (res-block 2 tail, writes d_out per flag)
__global__ __launch_bounds__(TPB) void instnorm_add_out_kernel(
    const bf16* __restrict__ t, const bf16* __restrict__ h,
    void* __restrict__ outp, const int* __restrict__ dflag, int HW)
{
    __shared__ float s1[16], s2[16];
    int bf = *dflag;
    long base = (long)blockIdx.x * HW;
    const bf16* p = t + base;
    const bf16* q = h + base;
    float sum = 0.f, sq = 0.f;
    for (int i = threadIdx.x; i < HW; i += TPB) { float v = toF(p[i]); sum += v; sq += v * v; }
    reduce2(sum, sq, s1, s2);
    float mean = sum / HW;
    float inv = rsqrtf(sq / HW - mean * mean + 1e-5f);
    for (int i = threadIdx.x; i < HW; i += TPB) {
        float v = toF(q[i]) + (toF(p[i]) - mean) * inv;
        if (bf) ((bf16*)outp)[base + i] = __float2bfloat16(v);
        else    ((float*)outp)[base + i] = v;
    }
}

// ---------------------------------------------------------------------------
// ws layout (fw = float* at byte 64):
//  [0..64)B   : dflag
//  BIASF  = 0        : packed fp32 biases (1715, pad 2048)
//  RB*T   = 2048..   : 4x resconv wT [2304][256] fp32 (589824 each)
//  FB     = 2361344  : multi-use 12 MB region:
//    layers: wT_dcn (off1T..dcn3T, ends FB+833833) | offb fp32 at FB+860160
//            (L2 extent FB+2433024 — overlaps h3 region but time-disjoint)
//    h3 bf16 at FB+2097152 (written layer-3 deform, live to end)
//    res:   t1 bf16 at FB+0, t2 bf16 at FB+1048576 (wT_dcn dead)
extern "C" void kernel_launch(void* const* d_in, const int* in_sizes, int n_in,
                              void* d_out, int out_size, void* d_ws, size_t ws_size,
                              hipStream_t stream) {
    const void* x      = d_in[0];
    const void* off1_w = d_in[1];  const void* off1_b = d_in[2];
    const void* dcn1_w = d_in[3];  const void* dcn1_b = d_in[4];
    const void* off2_w = d_in[5];  const void* off2_b = d_in[6];
    const void* dcn2_w = d_in[7];  const void* dcn2_b = d_in[8];
    const void* off3_w = d_in[9];  const void* off3_b = d_in[10];
    const void* dcn3_w = d_in[11]; const void* dcn3_b = d_in[12];
    const void* rb1_w1 = d_in[13]; const void* rb1_b1 = d_in[14];
    const void* rb1_w2 = d_in[15]; const void* rb1_b2 = d_in[16];
    const void* rb2_w1 = d_in[17]; const void* rb2_b1 = d_in[18];
    const void* rb2_w2 = d_in[19]; const void* rb2_b2 = d_in[20];

    const long SKIP1 = 2097152;
    const long SKIP2 = 10485760;

    int* dflag = (int*)d_ws;
    float* fw = (float*)((char*)d_ws + 64);

    const long BIASF = 0;
    const long RB1W1T = 2048;
    const long RB1W2T = RB1W1T + 589824;
    const long RB2W1T = RB1W2T + 589824;
    const long RB2W2T = RB2W1T + 589824;
    const long FB     = RB2W2T + 589824;      // 2361344
    const long OFF1T  = FB;
    const long DCN1T  = OFF1T + 21609;
    const long OFF2T  = DCN1T + 9408;
    const long DCN2T  = OFF2T + 49152;
    const long OFF3T  = DCN2T + 131072;
    const long DCN3T  = OFF3T + 98304;
    const long OFFB   = FB + 860160;
    const long H3F    = FB + 2097152;
    // bias sub-offsets
    const long OFF1B = BIASF + 0,   DCN1B = BIASF + 147;
    const long OFF2B = BIASF + 211, DCN2B = BIASF + 259;
    const long OFF3B = BIASF + 387, DCN3B = BIASF + 435;
    const long RB1B1 = BIASF + 691, RB1B2 = BIASF + 947;
    const long RB2B1 = BIASF + 1203, RB2B2 = BIASF + 1459;

    bf16* t1 = (bf16*)(fw + FB);
    bf16* t2 = (bf16*)(fw + FB + 1048576);
    bf16* h3 = (bf16*)(fw + H3F);
    float* offb = fw + OFFB;

    detect_kernel<<<1, 64, 0, stream>>>(x, dflag);

    // ---- weight repack + bias pack ----
    repack_kernel<<<85,   TPB, 0, stream>>>(off1_w, fw + OFF1T, dflag, 147, 147);
    repack_kernel<<<37,   TPB, 0, stream>>>(dcn1_w, fw + DCN1T, dflag, 64, 147);
    repack_kernel<<<192,  TPB, 0, stream>>>(off2_w, fw + OFF2T, dflag, 48, 1024);
    repack_kernel<<<512,  TPB, 0, stream>>>(dcn2_w, fw + DCN2T, dflag, 128, 1024);
    repack_kernel<<<384,  TPB, 0, stream>>>(off3_w, fw + OFF3T, dflag, 48, 2048);
    repack_kernel<<<1024, TPB, 0, stream>>>(dcn3_w, fw + DCN3T, dflag, 256, 2048);
    repack_kernel<<<1024, TPB, 0, stream>>>(rb1_w1, fw + RB1W1T, dflag, 256, 2304);
    repack_kernel<<<1024, TPB, 0, stream>>>(rb1_w2, fw + RB1W2T, dflag, 256, 2304);
    repack_kernel<<<1024, TPB, 0, stream>>>(rb2_w1, fw + RB2W1T, dflag, 256, 2304);
    repack_kernel<<<1024, TPB, 0, stream>>>(rb2_w2, fw + RB2W2T, dflag, 256, 2304);
    biaspack_kernel<<<1, TPB, 0, stream>>>(off1_b, dcn1_b, off2_b, dcn2_b, off3_b,
                                           dcn3_b, rb1_b1, rb1_b2, rb2_b1, rb2_b2,
                                           fw + BIASF, dflag);

    // ---- Layer 1 fused: offsets + deform, 7x7 s1 p3 ----
    layer1_kernel<<<4096, TPB, 0, stream>>>(
        x, fw + OFF1T, fw + DCN1T, fw + OFF1B, fw + DCN1B, d_out, SKIP1, dflag);
    instnorm_kernel<<<128, 1024, 0, stream>>>(d_out, SKIP1, 0, dflag, 65536, 1);

    // ---- Layer 2: 4x4 s2 p1, Cin=64 ----
    offconv_kernel<64, 4, 4, 2, 1, 8, 48, 64><<<4096, TPB, 0, stream>>>(
        d_out, SKIP1, fw + OFF2T, fw + OFF2B, offb, dflag, 256, 256, 128, 128);
    deform_kernel<0, 64, 4, 4, 2, 1, 8, 128, 128><<<4096, TPB, 0, stream>>>(
        d_out, SKIP1, offb, fw + DCN2T, fw + DCN2B, d_out, SKIP2, dflag, 256, 256, 128, 128);
    instnorm_kernel<<<256, 512, 0, stream>>>(d_out, SKIP2, 0, dflag, 16384, 1);

    // ---- Layer 3: 4x4 s2 p1, Cin=128; output bf16 h3 ----
    offconv_kernel<128, 4, 4, 2, 1, 4, 48, 64><<<2048, TPB, 0, stream>>>(
        d_out, SKIP2, fw + OFF3T, fw + OFF3B, offb, dflag, 128, 128, 64, 64);
    deform_kernel<1, 128, 4, 4, 2, 1, 4, 256, 256><<<2048, TPB, 0, stream>>>(
        d_out, SKIP2, offb, fw + DCN3T, fw + DCN3B, h3, 0, dflag, 128, 128, 64, 64);
    instnorm_kernel<<<512, TPB, 0, stream>>>(h3, 0, 1, dflag, 4096, 1);

    // ---- Res block 1 ---- (wT_dcn/offb dead; t1/t2 live)
    resconv_kernel<<<512, TPB, 0, stream>>>(h3, fw + RB1W1T, fw + RB1B1, t1);
    instnorm_kernel<<<512, TPB, 0, stream>>>(t1, 0, 1, dflag, 4096, 1);
    resconv_kernel<<<512, TPB, 0, stream>>>(t1, fw + RB1W2T, fw + RB1B2, t2);
    instnorm_add_kernel<<<512, TPB, 0, stream>>>(t2, h3, 4096);

    // ---- Res block 2 (final IN+add writes d_out per flag) ----
    resconv_kernel<<<512, TPB, 0, stream>>>(h3, fw + RB2W1T, fw + RB2B1, t1);
    instnorm_kernel<<<512, TPB, 0, stream>>>(t1, 0, 1, dflag, 4096, 1);
    resconv_kernel<<<512, TPB, 0, stream>>>(t1, fw + RB2W2T, fw + RB2B2, t2);
    instnorm_add_out_kernel<<<512, TPB, 0, stream>>>(t2, h3, d_out, dflag, 4096);
}

// Round 6
// 2260.063 us; speedup vs baseline: 4.4467x; 1.7718x over previous
//
#include <hip/hip_runtime.h>
#include <hip/hip_bf16.h>
#include <math.h>

#define TPB 256
typedef __hip_bfloat16 bf16;

// ---------------- ws layout constants (fp32-element offsets from fw) -------
constexpr long BIASF  = 0;          // 1715 packed fp32 biases (pad to 2048)
constexpr long RB1W1T = 2048;
constexpr long RB1W2T = 591872;
constexpr long RB2W1T = 1181696;
constexpr long RB2W2T = 1771520;
constexpr long FB     = 2361344;    // multi-use region
constexpr long OFF1T  = 2361344;
constexpr long DCN1T  = 2382953;
constexpr long OFF2T  = 2392361;
constexpr long DCN2T  = 2441513;
constexpr long OFF3T  = 2572585;
constexpr long DCN3T  = 2670889;    // ends 3195177
constexpr long OFFB   = 3221504;    // L2 offsets extent overlaps h3 (time-disjoint)
constexpr long H3F    = 4458496;
// bias sub-offsets
constexpr long OFF1B = 0,   DCN1B = 147;
constexpr long OFF2B = 211, DCN2B = 259;
constexpr long OFF3B = 387, DCN3B = 435;
constexpr long RB1B1 = 691, RB1B2 = 947;
constexpr long RB2B1 = 1203, RB2B2 = 1459;

// ---- compile-time dtype accessors (BF=1: bf16, BF=0: fp32) ----------------
template<int BF>
__device__ __forceinline__ float ldT(const void* p, long i) {
    if (BF) {
        unsigned short h = ((const unsigned short*)p)[i];
        return __uint_as_float(((unsigned int)h) << 16);
    }
    return ((const float*)p)[i];
}
template<int BF>
__device__ __forceinline__ void stT(void* p, long i, float v) {
    if (BF) ((bf16*)p)[i] = __float2bfloat16(v);
    else    ((float*)p)[i] = v;
}
__device__ __forceinline__ float toF(bf16 v) { return __bfloat162float(v); }
__device__ __forceinline__ float bitsToF(unsigned short h) {
    return __uint_as_float(((unsigned int)h) << 16);
}

// ---- dtype detector (validated rounds 3-5) --------------------------------
__global__ void detect_kernel(const void* __restrict__ x, int* __restrict__ flag) {
    if (threadIdx.x == 0 && blockIdx.x == 0) {
        const unsigned short* u = (const unsigned short*)x;
        int sane = 0;
        for (int i = 0; i < 256; ++i) {
            float v = bitsToF(u[i]);
            float a = fabsf(v);
            if (a > 0.0009f && a < 1100.f) ++sane;
        }
        *flag = (sane >= 224) ? 1 : 0;
    }
}

// ===========================================================================
// Fused repack: all 10 weight tensors -> transposed fp32 wT[S][Cout] in ws,
// plus all 10 bias vectors -> packed fp32 array. One launch.
// ===========================================================================
struct PtrPack { const void* p[20]; };   // p[0..9]=weights, p[10..19]=biases

template<int BF>
__device__ void repack_all_body(PtrPack pp, float* __restrict__ fw)
{
    constexpr int  bstart[11] = {0,22,32,80,208,304,816,1392,1968,2544,3120};
    constexpr int  sizes [10] = {21609,9408,49152,131072,98304,524288,589824,589824,589824,589824};
    constexpr int  coutA [10] = {147,64,48,128,48,256,256,256,256,256};
    constexpr int  sA    [10] = {147,147,1024,1024,2048,2048,2304,2304,2304,2304};
    constexpr long dstA  [10] = {OFF1T,DCN1T,OFF2T,DCN2T,OFF3T,DCN3T,RB1W1T,RB1W2T,RB2W1T,RB2W2T};
    constexpr int  bcum  [11] = {0,147,211,259,387,435,691,947,1203,1459,1715};

    int b = blockIdx.x;
    if (b < 3120) {
        int seg = 0;
        #pragma unroll
        for (int s = 1; s < 10; ++s) if (b >= bstart[s]) seg = s;
        const void* src = pp.p[seg];
        float* dst = fw + dstA[seg];
        int Cout = coutA[seg], S = sA[seg], sz = sizes[seg];
        int idx0 = (b - bstart[seg]) * 1024 + threadIdx.x * 4;
        #pragma unroll
        for (int j = 0; j < 4; ++j) {
            int idx = idx0 + j;
            if (idx < sz) {
                int co = idx / S, i = idx - co * S;
                dst[(long)i * Cout + co] = ldT<BF>(src, idx);
            }
        }
    } else {
        int j0 = (b - 3120) * 1024 + threadIdx.x * 4;
        #pragma unroll
        for (int q = 0; q < 4; ++q) {
            int j = j0 + q;
            if (j < 1715) {
                int v = 0;
                #pragma unroll
                for (int s = 1; s < 10; ++s) if (j >= bcum[s]) v = s;
                fw[BIASF + j] = ldT<BF>(pp.p[10 + v], j - bcum[v]);
            }
        }
    }
}
__global__ __launch_bounds__(TPB) void repack_all_kernel(
    PtrPack pp, float* fw, const int* dflag) {
    if (*dflag) repack_all_body<1>(pp, fw);
    else        repack_all_body<0>(pp, fw);
}

// ===========================================================================
// Fused layer 1: offset conv (147ch, 7x7, Cin=3) + deformable conv (64ch)
// One block = 32 consecutive pixels of one output row.
// Phase B/D: thread = (channel, 4-px group) -> coalesced weight loads + 4-acc ILP.
// ===========================================================================
template<int BF>
__device__ void layer1_body(const void* __restrict__ x, const float* __restrict__ wt1,
                            const float* __restrict__ wt2, const float* __restrict__ bias1,
                            const float* __restrict__ bias2, void* __restrict__ out,
                            long obase, float* xs, float* offs, float* smp)
{
    int b = blockIdx.x;
    int n = b >> 11;                // 2048 tiles per image
    int rt = b & 2047;
    int ho = rt >> 3;
    int wo0 = (rt & 7) << 5;
    long xn = (long)n * 3 * 65536;
    int t = threadIdx.x;

    // A: stage x patch: 3 ci x 7 rows x 38 cols (store stride 40), zero-pad
    for (int e = t; e < 3 * 7 * 40; e += TPB) {
        int cc = e % 40; int rr = (e / 40) % 7; int ci = e / 280;
        int yy = ho - 3 + rr; int xx = wo0 - 3 + cc;
        float v = 0.f;
        if (cc < 38 && yy >= 0 && yy < 256 && xx >= 0 && xx < 256)
            v = ldT<BF>(x, xn + (long)ci * 65536 + yy * 256 + xx);
        xs[e] = v;
    }
    __syncthreads();

    // B: offset conv; slot = (ch, 4-px group): wave reads 8 consecutive ch ->
    //    coalesced 32B weight loads; kx-unroll batches 7 loads; 4 indep accs.
    for (int e = t; e < 147 * 8; e += TPB) {
        int ch = e >> 3, pg = e & 7;
        int p0 = pg << 2;
        float bv = bias1[ch];
        float a0 = bv, a1 = bv, a2 = bv, a3 = bv;
        int i = 0;
        for (int ci = 0; ci < 3; ++ci)
            #pragma unroll
            for (int ky = 0; ky < 7; ++ky) {
                const float* xr = xs + (ci * 7 + ky) * 40 + p0;
                #pragma unroll
                for (int kx = 0; kx < 7; ++kx, ++i) {
                    float wv = wt1[i * 147 + ch];
                    a0 += wv * xr[kx];
                    a1 += wv * xr[kx + 1];
                    a2 += wv * xr[kx + 2];
                    a3 += wv * xr[kx + 3];
                }
            }
        float* orow = offs + ch * 32 + p0;
        orow[0] = a0; orow[1] = a1; orow[2] = a2; orow[3] = a3;
    }
    __syncthreads();

    // C: bilinear sampling with sigmoid mask: 147 (ci,k) rows x 32 px
    for (int e = t; e < 147 * 32; e += TPB) {
        int p = e & 31; int rest = e >> 5;
        int k = rest % 49; int ci = rest / 49;
        float oy = offs[k * 32 + p];
        float ox = offs[(49 + k) * 32 + p];
        float mr = offs[(98 + k) * 32 + p];
        float m = 1.f / (1.f + expf(-mr));
        float py = (float)(ho - 3 + k / 7) + oy;
        float px = (float)(wo0 + p - 3 + k % 7) + ox;
        float y0f = floorf(py), x0f = floorf(px);
        float wy = py - y0f, wx = px - x0f;
        int y0 = (int)y0f, x0 = (int)x0f;
        bool yv0 = (y0 >= 0) && (y0 < 256);
        bool yv1 = (y0 + 1 >= 0) && (y0 + 1 < 256);
        bool xv0 = (x0 >= 0) && (x0 < 256);
        bool xv1 = (x0 + 1 >= 0) && (x0 + 1 < 256);
        int y0c = min(max(y0, 0), 255), y1c = min(max(y0 + 1, 0), 255);
        int x0c = min(max(x0, 0), 255), x1c = min(max(x0 + 1, 0), 255);
        long xc = xn + (long)ci * 65536;
        float v00 = (yv0 && xv0) ? ldT<BF>(x, xc + y0c * 256 + x0c) : 0.f;
        float v01 = (yv0 && xv1) ? ldT<BF>(x, xc + y0c * 256 + x1c) : 0.f;
        float v10 = (yv1 && xv0) ? ldT<BF>(x, xc + y1c * 256 + x0c) : 0.f;
        float v11 = (yv1 && xv1) ? ldT<BF>(x, xc + y1c * 256 + x1c) : 0.f;
        float val = ((1.f - wy) * ((1.f - wx) * v00 + wx * v01) +
                     wy * ((1.f - wx) * v10 + wx * v11)) * m;
        smp[e] = val;
    }
    __syncthreads();

    // D: GEMM 64 cout x 147 k x 32 px; slot = (co, 4-px group), 2 iterations
    for (int e = t; e < 64 * 8; e += TPB) {
        int co = e >> 3, pg = e & 7;
        int p0 = pg << 2;
        float a0 = 0.f, a1 = 0.f, a2 = 0.f, a3 = 0.f;
        #pragma unroll 8
        for (int i = 0; i < 147; ++i) {
            float wv = wt2[i * 64 + co];
            const float4 v = *(const float4*)&smp[i * 32 + p0];
            a0 += wv * v.x; a1 += wv * v.y; a2 += wv * v.z; a3 += wv * v.w;
        }
        float bv = bias2[co];
        long ob = obase + ((long)(n * 64 + co) * 256 + ho) * 256 + wo0 + p0;
        stT<BF>(out, ob + 0, a0 + bv); stT<BF>(out, ob + 1, a1 + bv);
        stT<BF>(out, ob + 2, a2 + bv); stT<BF>(out, ob + 3, a3 + bv);
    }
}

__global__ __launch_bounds__(TPB) void layer1_kernel(
    const void* x, const float* wt1, const float* wt2,
    const float* bias1, const float* bias2, void* out, long obase, const int* dflag)
{
    __shared__ __align__(16) float xs[3 * 7 * 40];
    __shared__ __align__(16) float offs[147 * 32];
    __shared__ __align__(16) float smp[147 * 32];
    if (*dflag) layer1_body<1>(x, wt1, wt2, bias1, bias2, out, obase, xs, offs, smp);
    else        layer1_body<0>(x, wt1, wt2, bias1, bias2, out, obase, xs, offs, smp);
}

// ===========================================================================
// Offset conv for layers 2/3 (im2col patch-GEMM, transposed fp32 weights)
// ===========================================================================
template<int BF, int CIN, int KH, int KW, int ST, int PAD, int TPIX, int COUT, int COUTP>
__device__ void offconv_body(const void* __restrict__ x, long xbase,
                             const float* __restrict__ wt, const float* __restrict__ bias_f,
                             float* __restrict__ out, float* smp, int H, int W, int Ho, int Wo)
{
    constexpr int K = KH * KW, S = CIN * K;
    int tilesPerN = (Ho * Wo) / TPIX;
    int n = blockIdx.x / tilesPerN;
    int lp0 = (blockIdx.x % tilesPerN) * TPIX;
    long xn = xbase + (long)n * CIN * H * W;
    for (int e = threadIdx.x; e < S * TPIX; e += TPB) {
        int p = e % TPIX; int rest = e / TPIX;
        int k = rest % K; int ci = rest / K;
        int lp = lp0 + p;
        int ho = lp / Wo, wo = lp % Wo;
        int yy = ho * ST - PAD + k / KW;
        int xx = wo * ST - PAD + k % KW;
        float v = 0.f;
        if (yy >= 0 && yy < H && xx >= 0 && xx < W)
            v = ldT<BF>(x, xn + (long)ci * H * W + (long)yy * W + xx);
        smp[rest * TPIX + p] = v;
    }
    __syncthreads();
    constexpr int PXG = (TPIX * COUTP) / TPB;
    int co = threadIdx.x % COUTP;
    int g  = threadIdx.x / COUTP;
    if (co >= COUT) return;
    int pb = g * PXG;
    float acc[PXG];
    #pragma unroll
    for (int j = 0; j < PXG; ++j) acc[j] = 0.f;
    #pragma unroll 8
    for (int i = 0; i < S; ++i) {
        float wv = wt[(long)i * COUT + co];
        #pragma unroll
        for (int j = 0; j < PXG; ++j) acc[j] += wv * smp[i * TPIX + pb + j];
    }
    float bv = bias_f[co];
    int lp = lp0 + pb;
    int lr = lp / Wo, wo = lp % Wo;
    long ob = ((long)(n * COUT + co) * Ho + lr) * Wo + wo;
    #pragma unroll
    for (int j = 0; j < PXG; ++j) out[ob + j] = acc[j] + bv;
}

template<int CIN, int KH, int KW, int ST, int PAD, int TPIX, int COUT, int COUTP>
__global__ __launch_bounds__(TPB) void offconv_kernel(
    const void* x, long xbase, const float* wt, const float* bias_f, float* out,
    const int* dflag, int H, int W, int Ho, int Wo)
{
    __shared__ __align__(16) float smp[CIN * KH * KW * TPIX];
    if (*dflag)
        offconv_body<1, CIN, KH, KW, ST, PAD, TPIX, COUT, COUTP>(
            x, xbase, wt, bias_f, out, smp, H, W, Ho, Wo);
    else
        offconv_body<0, CIN, KH, KW, ST, PAD, TPIX, COUT, COUTP>(
            x, xbase, wt, bias_f, out, smp, H, W, Ho, Wo);
}

// ===========================================================================
// Deformable conv layers 2/3 (transposed fp32 weights, PXG=4 float4 GEMM)
// ===========================================================================
template<int BF, int OBF, int CIN, int KH, int KW, int ST, int PAD, int TPIX, int COUT, int COUTP>
__device__ void deform_body(const void* __restrict__ x, long xbase,
                            const float* __restrict__ off, const float* __restrict__ wt,
                            const float* __restrict__ bias_f, void* __restrict__ out,
                            long obase, float* smp, int H, int W, int Ho, int Wo)
{
    constexpr int K = KH * KW, S = CIN * K;
    int tilesPerN = (Ho * Wo) / TPIX;
    int n = blockIdx.x / tilesPerN;
    int lp0 = (blockIdx.x % tilesPerN) * TPIX;
    long xn = xbase + (long)n * CIN * H * W;
    const float* offn = off + (long)n * 3 * K * Ho * Wo;
    long planeSz = (long)Ho * Wo;

    for (int e = threadIdx.x; e < S * TPIX; e += TPB) {
        int p = e % TPIX; int rest = e / TPIX;
        int k = rest % K; int ci = rest / K;
        int lp = lp0 + p;
        int ho = lp / Wo, wo = lp % Wo;
        float oy = offn[(long)k * planeSz + lp];
        float ox = offn[(long)(K + k) * planeSz + lp];
        float mr = offn[(long)(2 * K + k) * planeSz + lp];
        float m = 1.f / (1.f + expf(-mr));
        float py = (float)(ho * ST - PAD + (k / KW)) + oy;
        float px = (float)(wo * ST - PAD + (k % KW)) + ox;
        float y0f = floorf(py), x0f = floorf(px);
        float wy = py - y0f, wx = px - x0f;
        int y0 = (int)y0f, x0 = (int)x0f;
        bool yv0 = (y0 >= 0) && (y0 < H);
        bool yv1 = (y0 + 1 >= 0) && (y0 + 1 < H);
        bool xv0 = (x0 >= 0) && (x0 < W);
        bool xv1 = (x0 + 1 >= 0) && (x0 + 1 < W);
        int y0c = min(max(y0, 0), H - 1), y1c = min(max(y0 + 1, 0), H - 1);
        int x0c = min(max(x0, 0), W - 1), x1c = min(max(x0 + 1, 0), W - 1);
        long xc = xn + (long)ci * H * W;
        float v00 = (yv0 && xv0) ? ldT<BF>(x, xc + (long)y0c * W + x0c) : 0.f;
        float v01 = (yv0 && xv1) ? ldT<BF>(x, xc + (long)y0c * W + x1c) : 0.f;
        float v10 = (yv1 && xv0) ? ldT<BF>(x, xc + (long)y1c * W + x0c) : 0.f;
        float v11 = (yv1 && xv1) ? ldT<BF>(x, xc + (long)y1c * W + x1c) : 0.f;
        float val = ((1.f - wy) * ((1.f - wx) * v00 + wx * v01) +
                     wy * ((1.f - wx) * v10 + wx * v11)) * m;
        smp[rest * TPIX + p] = val;
    }
    __syncthreads();

    constexpr int PXG = (TPIX * COUTP) / TPB;
    static_assert(PXG == 4, "deform GEMM assumes PXG==4");
    int co = threadIdx.x % COUTP;
    int g  = threadIdx.x / COUTP;
    int pb = g * PXG;
    float a0 = 0.f, a1 = 0.f, a2 = 0.f, a3 = 0.f;
    #pragma unroll 8
    for (int i = 0; i < S; ++i) {
        float wv = wt[(long)i * COUT + co];
        const float4 v = *(const float4*)&smp[i * TPIX + pb];
        a0 += wv * v.x; a1 += wv * v.y; a2 += wv * v.z; a3 += wv * v.w;
    }
    float bv = bias_f[co];
    int lp = lp0 + pb;
    int lr = lp / Wo, wo = lp % Wo;
    long ob = obase + ((long)(n * COUT + co) * Ho + lr) * Wo + wo;
    stT<OBF>(out, ob + 0, a0 + bv); stT<OBF>(out, ob + 1, a1 + bv);
    stT<OBF>(out, ob + 2, a2 + bv); stT<OBF>(out, ob + 3, a3 + bv);
}

template<int OUTWS, int CIN, int KH, int KW, int ST, int PAD, int TPIX, int COUT, int COUTP>
__global__ __launch_bounds__(TPB) void deform_kernel(
    const void* x, long xbase, const float* off, const float* wt, const float* bias_f,
    void* out, long obase, const int* dflag, int H, int W, int Ho, int Wo)
{
    __shared__ __align__(16) float smp[CIN * KH * KW * TPIX];
    if (*dflag)
        deform_body<1, 1, CIN, KH, KW, ST, PAD, TPIX, COUT, COUTP>(
            x, xbase, off, wt, bias_f, out, obase, smp, H, W, Ho, Wo);
    else
        deform_body<0, (OUTWS ? 1 : 0), CIN, KH, KW, ST, PAD, TPIX, COUT, COUTP>(
            x, xbase, off, wt, bias_f, out, obase, smp, H, W, Ho, Wo);
}

// ===========================================================================
// Res-block 3x3 reflect-pad conv, C=256, 64x64, bf16 in/out, fp32 wT (coalesced)
// ===========================================================================
__global__ __launch_bounds__(TPB) void resconv_kernel(
    const bf16* __restrict__ xin, const float* __restrict__ wt,
    const float* __restrict__ bias_f, bf16* __restrict__ out)
{
    __shared__ __align__(16) float xs[32 * 3 * 72];
    int b = blockIdx.x;
    int pxH = b & 1, coH = (b >> 1) & 1, r = (b >> 2) & 63, n = b >> 8;
    int t = threadIdx.x;
    int co = (t & 127) + coH * 128;
    int seg = t >> 7;                         // wave-uniform
    int px0 = pxH * 32 + seg * 16;
    int rows[3];
    rows[0] = (r == 0) ? 1 : r - 1;
    rows[1] = r;
    rows[2] = (r == 63) ? 62 : r + 1;
    float acc[16];
    #pragma unroll
    for (int j = 0; j < 16; ++j) acc[j] = 0.f;
    const unsigned short* xraw = (const unsigned short*)xin;

    for (int cc = 0; cc < 8; ++cc) {
        __syncthreads();
        for (int e = t; e < 32 * 3 * 72; e += TPB) {
            int col = e % 72; int rr = (e / 72) % 3; int ci = e / 216;
            int c = col - 2;
            c = (c < 0) ? -c : ((c > 63) ? 126 - c : c);
            xs[e] = bitsToF(xraw[((long)(n * 256 + cc * 32 + ci)) * 4096 + rows[rr] * 64 + c]);
        }
        __syncthreads();
        for (int ci = 0; ci < 32; ++ci) {
            int cig = cc * 32 + ci;
            float w9[9];
            #pragma unroll
            for (int q = 0; q < 9; ++q) w9[q] = wt[((long)cig * 9 + q) * 256 + co];
            float X[3][20];
            #pragma unroll
            for (int rr = 0; rr < 3; ++rr) {
                int base = (ci * 3 + rr) * 72 + px0;   // 16B-aligned, broadcast
                #pragma unroll
                for (int q = 0; q < 20; ++q) X[rr][q] = xs[base + q];
            }
            #pragma unroll
            for (int rr = 0; rr < 3; ++rr)
                #pragma unroll
                for (int dx = 0; dx < 3; ++dx) {
                    float wv = w9[rr * 3 + dx];
                    #pragma unroll
                    for (int j = 0; j < 16; ++j) acc[j] += wv * X[rr][j + dx + 1];
                }
        }
    }
    float bv = bias_f[co];
    long ob = ((long)(n * 256 + co)) * 4096 + r * 64 + px0;
    #pragma unroll
    for (int j = 0; j < 16; ++j) out[ob + j] = __float2bfloat16(acc[j] + bv);
}

// ---------------- block reduction (up to 16 waves) -------------------------
__device__ __forceinline__ void reduce2(float& sum, float& sq, float* s1, float* s2)
{
    for (int off = 32; off; off >>= 1) {
        sum += __shfl_down(sum, off, 64);
        sq  += __shfl_down(sq,  off, 64);
    }
    int nw = blockDim.x >> 6;
    int wid = threadIdx.x >> 6;
    if ((threadIdx.x & 63) == 0) { s1[wid] = sum; s2[wid] = sq; }
    __syncthreads();
    sum = 0.f; sq = 0.f;
    for (int w = 0; w < nw; ++w) { sum += s1[w]; sq += s2[w]; }
}

// ---------------- instance norm (in place), optional relu ------------------
__global__ void instnorm_kernel(
    void* __restrict__ buf, long base0, int isWS, const int* __restrict__ dflag,
    int HW, int relu)
{
    __shared__ float s1[16], s2[16];
    int bf = isWS ? 1 : *dflag;
    long base = base0 + (long)blockIdx.x * HW;
    float sum = 0.f, sq = 0.f;
    for (int i = threadIdx.x; i < HW; i += blockDim.x) {
        float v = bf ? bitsToF(((const unsigned short*)buf)[base + i])
                     : ((const float*)buf)[base + i];
        sum += v; sq += v * v;
    }
    reduce2(sum, sq, s1, s2);
    float mean = sum / HW;
    float inv = rsqrtf(sq / HW - mean * mean + 1e-5f);
    for (int i = threadIdx.x; i < HW; i += blockDim.x) {
        float v = bf ? bitsToF(((const unsigned short*)buf)[base + i])
                     : ((const float*)buf)[base + i];
        v = (v - mean) * inv;
        if (relu) v = fmaxf(v, 0.f);
        if (bf) ((bf16*)buf)[base + i] = __float2bfloat16(v);
        else    ((float*)buf)[base + i] = v;
    }
}

// h += IN(t)   (bf16 ws chain, res-block 1 tail)
__global__ __launch_bounds__(TPB) void instnorm_add_kernel(
    const bf16* __restrict__ t, bf16* __restrict__ h, int HW)
{
    __shared__ float s1[16], s2[16];
    long base = (long)blockIdx.x * HW;
    const bf16* p = t + base;
    bf16* q = h + base;
    float sum = 0.f, sq = 0.f;
    for (int i = threadIdx.x; i < HW; i += TPB) { float v = toF(p[i]); sum += v; sq += v * v; }
    reduce2(sum, sq, s1, s2);
    float mean = sum / HW;
    float inv = rsqrtf(sq / HW - mean * mean + 1e-5f);
    for (int i = threadIdx.x; i < HW; i += TPB)
        q[i] = __float2bfloat16(toF(q[i]) + (toF(p[i]) - mean) * inv);
}

// out = h + IN(t)   (res-block 2 tail, writes d_out per flag)
__global__ __launch_bounds__(TPB) void instnorm_add_out_kernel(
    const bf16* __restrict__ t, const bf16* __restrict__ h,
    void* __restrict__ outp, const int* __restrict__ dflag, int HW)
{
    __shared__ float s1[16], s2[16];
    int bf = *dflag;
    long base = (long)blockIdx.x * HW;
    const bf16* p = t + base;
    const bf16* q = h + base;
    float sum = 0.f, sq = 0.f;
    for (int i = threadIdx.x; i < HW; i += TPB) { float v = toF(p[i]); sum += v; sq += v * v; }
    reduce2(sum, sq, s1, s2);
    float mean = sum / HW;
    float inv = rsqrtf(sq / HW - mean * mean + 1e-5f);
    for (int i = threadIdx.x; i < HW; i += TPB) {
        float v = toF(q[i]) + (toF(p[i]) - mean) * inv;
        if (bf) ((bf16*)outp)[base + i] = __float2bfloat16(v);
        else    ((float*)outp)[base + i] = v;
    }
}

// ---------------------------------------------------------------------------
extern "C" void kernel_launch(void* const* d_in, const int* in_sizes, int n_in,
                              void* d_out, int out_size, void* d_ws, size_t ws_size,
                              hipStream_t stream) {
    const void* x = d_in[0];

    const long SKIP1 = 2097152;
    const long SKIP2 = 10485760;

    int* dflag = (int*)d_ws;
    float* fw = (float*)((char*)d_ws + 64);

    bf16* t1 = (bf16*)(fw + FB);
    bf16* t2 = (bf16*)(fw + FB + 1048576);
    bf16* h3 = (bf16*)(fw + H3F);
    float* offb = fw + OFFB;

    detect_kernel<<<1, 64, 0, stream>>>(x, dflag);

    // ---- fused weight/bias repack (one launch) ----
    PtrPack pp;
    pp.p[0] = d_in[1];  pp.p[1] = d_in[3];  pp.p[2] = d_in[5];  pp.p[3] = d_in[7];
    pp.p[4] = d_in[9];  pp.p[5] = d_in[11]; pp.p[6] = d_in[13]; pp.p[7] = d_in[15];
    pp.p[8] = d_in[17]; pp.p[9] = d_in[19];
    pp.p[10] = d_in[2];  pp.p[11] = d_in[4];  pp.p[12] = d_in[6];  pp.p[13] = d_in[8];
    pp.p[14] = d_in[10]; pp.p[15] = d_in[12]; pp.p[16] = d_in[14]; pp.p[17] = d_in[16];
    pp.p[18] = d_in[18]; pp.p[19] = d_in[20];
    repack_all_kernel<<<3122, TPB, 0, stream>>>(pp, fw, dflag);

    // ---- Layer 1 fused: offsets + deform, 7x7 s1 p3 ----
    layer1_kernel<<<4096, TPB, 0, stream>>>(
        x, fw + OFF1T, fw + DCN1T, fw + OFF1B, fw + DCN1B, d_out, SKIP1, dflag);
    instnorm_kernel<<<128, 1024, 0, stream>>>(d_out, SKIP1, 0, dflag, 65536, 1);

    // ---- Layer 2: 4x4 s2 p1, Cin=64 ----
    offconv_kernel<64, 4, 4, 2, 1, 8, 48, 64><<<4096, TPB, 0, stream>>>(
        d_out, SKIP1, fw + OFF2T, fw + OFF2B, offb, dflag, 256, 256, 128, 128);
    deform_kernel<0, 64, 4, 4, 2, 1, 8, 128, 128><<<4096, TPB, 0, stream>>>(
        d_out, SKIP1, offb, fw + DCN2T, fw + DCN2B, d_out, SKIP2, dflag, 256, 256, 128, 128);
    instnorm_kernel<<<256, 512, 0, stream>>>(d_out, SKIP2, 0, dflag, 16384, 1);

    // ---- Layer 3: 4x4 s2 p1, Cin=128; output bf16 h3 ----
    offconv_kernel<128, 4, 4, 2, 1, 4, 48, 64><<<2048, TPB, 0, stream>>>(
        d_out, SKIP2, fw + OFF3T, fw + OFF3B, offb, dflag, 128, 128, 64, 64);
    deform_kernel<1, 128, 4, 4, 2, 1, 4, 256, 256><<<2048, TPB, 0, stream>>>(
        d_out, SKIP2, offb, fw + DCN3T, fw + DCN3B, h3, 0, dflag, 128, 128, 64, 64);
    instnorm_kernel<<<512, TPB, 0, stream>>>(h3, 0, 1, dflag, 4096, 1);

    // ---- Res block 1 ---- (wT_dcn/offb dead; t1/t2 live)
    resconv_kernel<<<512, TPB, 0, stream>>>(h3, fw + RB1W1T, fw + RB1B1, t1);
    instnorm_kernel<<<512, TPB, 0, stream>>>(t1, 0, 1, dflag, 4096, 1);
    resconv_kernel<<<512, TPB, 0, stream>>>(t1, fw + RB1W2T, fw + RB1B2, t2);
    instnorm_add_kernel<<<512, TPB, 0, stream>>>(t2, h3, 4096);

    // ---- Res block 2 (final IN+add writes d_out per flag) ----
    resconv_kernel<<<512, TPB, 0, stream>>>(h3, fw + RB2W1T, fw + RB2B1, t1);
    instnorm_kernel<<<512, TPB, 0, stream>>>(t1, 0, 1, dflag, 4096, 1);
    resconv_kernel<<<512, TPB, 0, stream>>>(t1, fw + RB2W2T, fw + RB2B2, t2);
    instnorm_add_out_kernel<<<512, TPB, 0, stream>>>(t2, h3, d_out, dflag, 4096);
}

// Round 9
// 2089.385 us; speedup vs baseline: 4.8099x; 1.0817x over previous
//
#include <hip/hip_runtime.h>
#include <hip/hip_bf16.h>
#include <math.h>

#define TPB 256
typedef __hip_bfloat16 bf16;

// ---------------- ws layout constants (fp32-element offsets from fw) -------
constexpr long BIASF  = 0;          // 1715 packed fp32 biases (pad to 2048)
constexpr long RB1W1T = 2048;
constexpr long RB1W2T = 591872;
constexpr long RB2W1T = 1181696;
constexpr long RB2W2T = 1771520;
constexpr long FB     = 2361344;    // multi-use region
constexpr long OFF1T  = 2361344;
constexpr long DCN1T  = 2382953;
constexpr long OFF2T  = 2392361;
constexpr long DCN2T  = 2441513;
constexpr long OFF3T  = 2572585;
constexpr long DCN3T  = 2670889;    // ends 3195177
constexpr long OFFB   = 3221504;    // offsets during layers (dead at res time)
constexpr long H3F    = 4458496;
// bias sub-offsets
constexpr long OFF1B = 0,   DCN1B = 147;
constexpr long OFF2B = 211, DCN2B = 259;
constexpr long OFF3B = 387, DCN3B = 435;
constexpr long RB1B1 = 691, RB1B2 = 947;
constexpr long RB2B1 = 1203, RB2B2 = 1459;
// NOTE (R7/R8 post-mortems): NO extra partial buffers exist. t1/t2 occupy
// [FB, H3F) as bf16; h3 at [H3F, H3F+1048576). resconv is split by PIXELS
// (grid 1024) so it needs no split-K partial buffer.

// ---- compile-time dtype accessors (BF=1: bf16, BF=0: fp32) ----------------
template<int BF>
__device__ __forceinline__ float ldT(const void* p, long i) {
    if (BF) {
        unsigned short h = ((const unsigned short*)p)[i];
        return __uint_as_float(((unsigned int)h) << 16);
    }
    return ((const float*)p)[i];
}
template<int BF>
__device__ __forceinline__ void stT(void* p, long i, float v) {
    if (BF) ((bf16*)p)[i] = __float2bfloat16(v);
    else    ((float*)p)[i] = v;
}
__device__ __forceinline__ float toF(bf16 v) { return __bfloat162float(v); }
__device__ __forceinline__ float bitsToF(unsigned short h) {
    return __uint_as_float(((unsigned int)h) << 16);
}

// ---- dtype detector (validated rounds 3-6) --------------------------------
__global__ void detect_kernel(const void* __restrict__ x, int* __restrict__ flag) {
    if (threadIdx.x == 0 && blockIdx.x == 0) {
        const unsigned short* u = (const unsigned short*)x;
        int sane = 0;
        for (int i = 0; i < 256; ++i) {
            float v = bitsToF(u[i]);
            float a = fabsf(v);
            if (a > 0.0009f && a < 1100.f) ++sane;
        }
        *flag = (sane >= 224) ? 1 : 0;
    }
}

// ===========================================================================
// Fused repack: all 10 weight tensors -> transposed fp32 wT[S][Cout] in ws,
// plus all 10 bias vectors -> packed fp32 array. One launch.
// ===========================================================================
struct PtrPack { const void* p[20]; };   // p[0..9]=weights, p[10..19]=biases

template<int BF>
__device__ void repack_all_body(PtrPack pp, float* __restrict__ fw)
{
    constexpr int  bstart[11] = {0,22,32,80,208,304,816,1392,1968,2544,3120};
    constexpr int  sizes [10] = {21609,9408,49152,131072,98304,524288,589824,589824,589824,589824};
    constexpr int  coutA [10] = {147,64,48,128,48,256,256,256,256,256};
    constexpr int  sA    [10] = {147,147,1024,1024,2048,2048,2304,2304,2304,2304};
    constexpr long dstA  [10] = {OFF1T,DCN1T,OFF2T,DCN2T,OFF3T,DCN3T,RB1W1T,RB1W2T,RB2W1T,RB2W2T};
    constexpr int  bcum  [11] = {0,147,211,259,387,435,691,947,1203,1459,1715};

    int b = blockIdx.x;
    if (b < 3120) {
        int seg = 0;
        #pragma unroll
        for (int s = 1; s < 10; ++s) if (b >= bstart[s]) seg = s;
        const void* src = pp.p[seg];
        float* dst = fw + dstA[seg];
        int Cout = coutA[seg], S = sA[seg], sz = sizes[seg];
        int idx0 = (b - bstart[seg]) * 1024 + threadIdx.x * 4;
        #pragma unroll
        for (int j = 0; j < 4; ++j) {
            int idx = idx0 + j;
            if (idx < sz) {
                int co = idx / S, i = idx - co * S;
                dst[(long)i * Cout + co] = ldT<BF>(src, idx);
            }
        }
    } else {
        int j0 = (b - 3120) * 1024 + threadIdx.x * 4;
        #pragma unroll
        for (int q = 0; q < 4; ++q) {
            int j = j0 + q;
            if (j < 1715) {
                int v = 0;
                #pragma unroll
                for (int s = 1; s < 10; ++s) if (j >= bcum[s]) v = s;
                fw[BIASF + j] = ldT<BF>(pp.p[10 + v], j - bcum[v]);
            }
        }
    }
}
__global__ __launch_bounds__(TPB) void repack_all_kernel(
    PtrPack pp, float* fw, const int* dflag) {
    if (*dflag) repack_all_body<1>(pp, fw);
    else        repack_all_body<0>(pp, fw);
}

// ===========================================================================
// Fused layer 1: offset conv (147ch, 7x7, Cin=3) + deformable conv (64ch)
// ===========================================================================
template<int BF>
__device__ void layer1_body(const void* __restrict__ x, const float* __restrict__ wt1,
                            const float* __restrict__ wt2, const float* __restrict__ bias1,
                            const float* __restrict__ bias2, void* __restrict__ out,
                            long obase, float* xs, float* offs, float* smp)
{
    int b = blockIdx.x;
    int n = b >> 11;                // 2048 tiles per image
    int rt = b & 2047;
    int ho = rt >> 3;
    int wo0 = (rt & 7) << 5;
    long xn = (long)n * 3 * 65536;
    int t = threadIdx.x;

    // A: stage x patch: 3 ci x 7 rows x 38 cols (store stride 40), zero-pad
    for (int e = t; e < 3 * 7 * 40; e += TPB) {
        int cc = e % 40; int rr = (e / 40) % 7; int ci = e / 280;
        int yy = ho - 3 + rr; int xx = wo0 - 3 + cc;
        float v = 0.f;
        if (cc < 38 && yy >= 0 && yy < 256 && xx >= 0 && xx < 256)
            v = ldT<BF>(x, xn + (long)ci * 65536 + yy * 256 + xx);
        xs[e] = v;
    }
    __syncthreads();

    // B: offset conv; slot = (ch, 4-px group): coalesced weight loads, 4 accs
    for (int e = t; e < 147 * 8; e += TPB) {
        int ch = e >> 3, pg = e & 7;
        int p0 = pg << 2;
        float bv = bias1[ch];
        float a0 = bv, a1 = bv, a2 = bv, a3 = bv;
        int i = 0;
        for (int ci = 0; ci < 3; ++ci)
            #pragma unroll
            for (int ky = 0; ky < 7; ++ky) {
                const float* xr = xs + (ci * 7 + ky) * 40 + p0;
                #pragma unroll
                for (int kx = 0; kx < 7; ++kx, ++i) {
                    float wv = wt1[i * 147 + ch];
                    a0 += wv * xr[kx];
                    a1 += wv * xr[kx + 1];
                    a2 += wv * xr[kx + 2];
                    a3 += wv * xr[kx + 3];
                }
            }
        float* orow = offs + ch * 32 + p0;
        orow[0] = a0; orow[1] = a1; orow[2] = a2; orow[3] = a3;
    }
    __syncthreads();

    // C: bilinear sampling with sigmoid mask: 147 (ci,k) rows x 32 px
    for (int e = t; e < 147 * 32; e += TPB) {
        int p = e & 31; int rest = e >> 5;
        int k = rest % 49; int ci = rest / 49;
        float oy = offs[k * 32 + p];
        float ox = offs[(49 + k) * 32 + p];
        float mr = offs[(98 + k) * 32 + p];
        float m = 1.f / (1.f + expf(-mr));
        float py = (float)(ho - 3 + k / 7) + oy;
        float px = (float)(wo0 + p - 3 + k % 7) + ox;
        float y0f = floorf(py), x0f = floorf(px);
        float wy = py - y0f, wx = px - x0f;
        int y0 = (int)y0f, x0 = (int)x0f;
        bool yv0 = (y0 >= 0) && (y0 < 256);
        bool yv1 = (y0 + 1 >= 0) && (y0 + 1 < 256);
        bool xv0 = (x0 >= 0) && (x0 < 256);
        bool xv1 = (x0 + 1 >= 0) && (x0 + 1 < 256);
        int y0c = min(max(y0, 0), 255), y1c = min(max(y0 + 1, 0), 255);
        int x0c = min(max(x0, 0), 255), x1c = min(max(x0 + 1, 0), 255);
        long xc = xn + (long)ci * 65536;
        float v00 = (yv0 && xv0) ? ldT<BF>(x, xc + y0c * 256 + x0c) : 0.f;
        float v01 = (yv0 && xv1) ? ldT<BF>(x, xc + y0c * 256 + x1c) : 0.f;
        float v10 = (yv1 && xv0) ? ldT<BF>(x, xc + y1c * 256 + x0c) : 0.f;
        float v11 = (yv1 && xv1) ? ldT<BF>(x, xc + y1c * 256 + x1c) : 0.f;
        float val = ((1.f - wy) * ((1.f - wx) * v00 + wx * v01) +
                     wy * ((1.f - wx) * v10 + wx * v11)) * m;
        smp[e] = val;
    }
    __syncthreads();

    // D: GEMM 64 cout x 147 k x 32 px; slot = (co, 4-px group)
    for (int e = t; e < 64 * 8; e += TPB) {
        int co = e >> 3, pg = e & 7;
        int p0 = pg << 2;
        float a0 = 0.f, a1 = 0.f, a2 = 0.f, a3 = 0.f;
        #pragma unroll 8
        for (int i = 0; i < 147; ++i) {
            float wv = wt2[i * 64 + co];
            const float4 v = *(const float4*)&smp[i * 32 + p0];
            a0 += wv * v.x; a1 += wv * v.y; a2 += wv * v.z; a3 += wv * v.w;
        }
        float bv = bias2[co];
        long ob = obase + ((long)(n * 64 + co) * 256 + ho) * 256 + wo0 + p0;
        stT<BF>(out, ob + 0, a0 + bv); stT<BF>(out, ob + 1, a1 + bv);
        stT<BF>(out, ob + 2, a2 + bv); stT<BF>(out, ob + 3, a3 + bv);
    }
}

__global__ __launch_bounds__(TPB) void layer1_kernel(
    const void* x, const float* wt1, const float* wt2,
    const float* bias1, const float* bias2, void* out, long obase, const int* dflag)
{
    __shared__ __align__(16) float xs[3 * 7 * 40];
    __shared__ __align__(16) float offs[147 * 32];
    __shared__ __align__(16) float smp[147 * 32];
    if (*dflag) layer1_body<1>(x, wt1, wt2, bias1, bias2, out, obase, xs, offs, smp);
    else        layer1_body<0>(x, wt1, wt2, bias1, bias2, out, obase, xs, offs, smp);
}

// ===========================================================================
// Offset conv for layers 2/3 (im2col patch-GEMM, transposed fp32 weights)
// ===========================================================================
template<int BF, int CIN, int KH, int KW, int ST, int PAD, int TPIX, int COUT, int COUTP>
__device__ void offconv_body(const void* __restrict__ x, long xbase,
                             const float* __restrict__ wt, const float* __restrict__ bias_f,
                             float* __restrict__ out, float* smp, int H, int W, int Ho, int Wo)
{
    constexpr int K = KH * KW, S = CIN * K;
    int tilesPerN = (Ho * Wo) / TPIX;
    int n = blockIdx.x / tilesPerN;
    int lp0 = (blockIdx.x % tilesPerN) * TPIX;
    long xn = xbase + (long)n * CIN * H * W;
    for (int e = threadIdx.x; e < S * TPIX; e += TPB) {
        int p = e % TPIX; int rest = e / TPIX;
        int k = rest % K; int ci = rest / K;
        int lp = lp0 + p;
        int ho = lp / Wo, wo = lp % Wo;
        int yy = ho * ST - PAD + k / KW;
        int xx = wo * ST - PAD + k % KW;
        float v = 0.f;
        if (yy >= 0 && yy < H && xx >= 0 && xx < W)
            v = ldT<BF>(x, xn + (long)ci * H * W + (long)yy * W + xx);
        smp[rest * TPIX + p] = v;
    }
    __syncthreads();
    constexpr int PXG = (TPIX * COUTP) / TPB;
    int co = threadIdx.x % COUTP;
    int g  = threadIdx.x / COUTP;
    if (co >= COUT) return;
    int pb = g * PXG;
    float acc[PXG];
    #pragma unroll
    for (int j = 0; j < PXG; ++j) acc[j] = 0.f;
    #pragma unroll 8
    for (int i = 0; i < S; ++i) {
        float wv = wt[(long)i * COUT + co];
        #pragma unroll
        for (int j = 0; j < PXG; ++j) acc[j] += wv * smp[i * TPIX + pb + j];
    }
    float bv = bias_f[co];
    int lp = lp0 + pb;
    int lr = lp / Wo, wo = lp % Wo;
    long ob = ((long)(n * COUT + co) * Ho + lr) * Wo + wo;
    #pragma unroll
    for (int j = 0; j < PXG; ++j) out[ob + j] = acc[j] + bv;
}

template<int CIN, int KH, int KW, int ST, int PAD, int TPIX, int COUT, int COUTP>
__global__ __launch_bounds__(TPB) void offconv_kernel(
    const void* x, long xbase, const float* wt, const float* bias_f, float* out,
    const int* dflag, int H, int W, int Ho, int Wo)
{
    __shared__ __align__(16) float smp[CIN * KH * KW * TPIX];
    if (*dflag)
        offconv_body<1, CIN, KH, KW, ST, PAD, TPIX, COUT, COUTP>(
            x, xbase, wt, bias_f, out, smp, H, W, Ho, Wo);
    else
        offconv_body<0, CIN, KH, KW, ST, PAD, TPIX, COUT, COUTP>(
            x, xbase, wt, bias_f, out, smp, H, W, Ho, Wo);
}

// ===========================================================================
// Deformable conv layers 2/3 (transposed fp32 weights, PXG=4 float4 GEMM)
// ===========================================================================
template<int BF, int OBF, int CIN, int KH, int KW, int ST, int PAD, int TPIX, int COUT, int COUTP>
__device__ void deform_body(const void* __restrict__ x, long xbase,
                            const float* __restrict__ off, const float* __restrict__ wt,
                            const float* __restrict__ bias_f, void* __restrict__ out,
                            long obase, float* smp, int H, int W, int Ho, int Wo)
{
    constexpr int K = KH * KW, S = CIN * K;
    int tilesPerN = (Ho * Wo) / TPIX;
    int n = blockIdx.x / tilesPerN;
    int lp0 = (blockIdx.x % tilesPerN) * TPIX;
    long xn = xbase + (long)n * CIN * H * W;
    const float* offn = off + (long)n * 3 * K * Ho * Wo;
    long planeSz = (long)Ho * Wo;

    for (int e = threadIdx.x; e < S * TPIX; e += TPB) {
        int p = e % TPIX; int rest = e / TPIX;
        int k = rest % K; int ci = rest / K;
        int lp = lp0 + p;
        int ho = lp / Wo, wo = lp % Wo;
        float oy = offn[(long)k * planeSz + lp];
        float ox = offn[(long)(K + k) * planeSz + lp];
        float mr = offn[(long)(2 * K + k) * planeSz + lp];
        float m = 1.f / (1.f + expf(-mr));
        float py = (float)(ho * ST - PAD + (k / KW)) + oy;
        float px = (float)(wo * ST - PAD + (k % KW)) + ox;
        float y0f = floorf(py), x0f = floorf(px);
        float wy = py - y0f, wx = px - x0f;
        int y0 = (int)y0f, x0 = (int)x0f;
        bool yv0 = (y0 >= 0) && (y0 < H);
        bool yv1 = (y0 + 1 >= 0) && (y0 + 1 < H);
        bool xv0 = (x0 >= 0) && (x0 < W);
        bool xv1 = (x0 + 1 >= 0) && (x0 + 1 < W);
        int y0c = min(max(y0, 0), H - 1), y1c = min(max(y0 + 1, 0), H - 1);
        int x0c = min(max(x0, 0), W - 1), x1c = min(max(x0 + 1, 0), W - 1);
        long xc = xn + (long)ci * H * W;
        float v00 = (yv0 && xv0) ? ldT<BF>(x, xc + (long)y0c * W + x0c) : 0.f;
        float v01 = (yv0 && xv1) ? ldT<BF>(x, xc + (long)y0c * W + x1c) : 0.f;
        float v10 = (yv1 && xv0) ? ldT<BF>(x, xc + (long)y1c * W + x0c) : 0.f;
        float v11 = (yv1 && xv1) ? ldT<BF>(x, xc + (long)y1c * W + x1c) : 0.f;
        float val = ((1.f - wy) * ((1.f - wx) * v00 + wx * v01) +
                     wy * ((1.f - wx) * v10 + wx * v11)) * m;
        smp[rest * TPIX + p] = val;
    }
    __syncthreads();

    constexpr int PXG = (TPIX * COUTP) / TPB;
    static_assert(PXG == 4, "deform GEMM assumes PXG==4");
    int co = threadIdx.x % COUTP;
    int g  = threadIdx.x / COUTP;
    int pb = g * PXG;
    float a0 = 0.f, a1 = 0.f, a2 = 0.f, a3 = 0.f;
    #pragma unroll 8
    for (int i = 0; i < S; ++i) {
        float wv = wt[(long)i * COUT + co];
        const float4 v = *(const float4*)&smp[i * TPIX + pb];
        a0 += wv * v.x; a1 += wv * v.y; a2 += wv * v.z; a3 += wv * v.w;
    }
    float bv = bias_f[co];
    int lp = lp0 + pb;
    int lr = lp / Wo, wo = lp % Wo;
    long ob = obase + ((long)(n * COUT + co) * Ho + lr) * Wo + wo;
    stT<OBF>(out, ob + 0, a0 + bv); stT<OBF>(out, ob + 1, a1 + bv);
    stT<OBF>(out, ob + 2, a2 + bv); stT<OBF>(out, ob + 3, a3 + bv);
}

template<int OUTWS, int CIN, int KH, int KW, int ST, int PAD, int TPIX, int COUT, int COUTP>
__global__ __launch_bounds__(TPB) void deform_kernel(
    const void* x, long xbase, const float* off, const float* wt, const float* bias_f,
    void* out, long obase, const int* dflag, int H, int W, int Ho, int Wo)
{
    __shared__ __align__(16) float smp[CIN * KH * KW * TPIX];
    if (*dflag)
        deform_body<1, 1, CIN, KH, KW, ST, PAD, TPIX, COUT, COUTP>(
            x, xbase, off, wt, bias_f, out, obase, smp, H, W, Ho, Wo);
    else
        deform_body<0, (OUTWS ? 1 : 0), CIN, KH, KW, ST, PAD, TPIX, COUT, COUTP>(
            x, xbase, off, wt, bias_f, out, obase, smp, H, W, Ho, Wo);
}

// ===========================================================================
// Res-block 3x3 reflect-pad conv, C=256, 64x64, bf16 in/out, fp32 wT.
// Split by PIXELS: block = (n, r, coHalf, pxQuarter), grid 1024 (4 blk/CU).
// Thread = (co in half, 8-px group). LDS stages a 20-col window per 32-ci
// chunk (7.7 KB); X reads are aligned float4 wave-broadcasts.
// ===========================================================================
__global__ __launch_bounds__(TPB) void resconv_kernel(
    const bf16* __restrict__ xin, const float* __restrict__ wt,
    const float* __restrict__ bias_f, bf16* __restrict__ out)
{
    __shared__ __align__(16) float xs[32 * 3 * 20];
    int b = blockIdx.x;
    int pxQ = b & 3, coH = (b >> 2) & 1, r = (b >> 3) & 63, n = b >> 9;
    int t = threadIdx.x;
    int co = (t & 127) + coH * 128;
    int pg = t >> 7;                     // wave-uniform (waves 0,1 / 2,3)
    int px0 = pxQ * 16;
    int rows[3];
    rows[0] = (r == 0) ? 1 : r - 1;
    rows[1] = r;
    rows[2] = (r == 63) ? 62 : r + 1;
    float acc[8];
    #pragma unroll
    for (int j = 0; j < 8; ++j) acc[j] = 0.f;
    const unsigned short* xraw = (const unsigned short*)xin;

    for (int cc = 0; cc < 8; ++cc) {
        __syncthreads();
        // stage 32 ci x 3 rows x 20 cols; store col c <-> global col px0-1+c
        for (int e = t; e < 32 * 3 * 20; e += TPB) {
            int col = e % 20; int rr = (e / 20) % 3; int ci = e / 60;
            int gx = px0 - 1 + col;
            gx = (gx < 0) ? -gx : ((gx > 63) ? 126 - gx : gx);
            xs[e] = bitsToF(xraw[((long)(n * 256 + cc * 32 + ci)) * 4096 + rows[rr] * 64 + gx]);
        }
        __syncthreads();
        for (int ci = 0; ci < 32; ++ci) {
            int cig = cc * 32 + ci;
            float w9[9];
            #pragma unroll
            for (int q = 0; q < 9; ++q) w9[q] = wt[((long)cig * 9 + q) * 256 + co];
            // X[q] <-> store col pg*8+q <-> global col px0-1+pg*8+q.
            // Output px = px0+pg*8+j needs input cols px-1..px+1 -> X[j+dx].
            float X[3][12];
            #pragma unroll
            for (int rr = 0; rr < 3; ++rr) {
                const float4* p4 = (const float4*)&xs[(ci * 3 + rr) * 20 + pg * 8];
                float4 A = p4[0], B = p4[1], C = p4[2];
                X[rr][0] = A.x; X[rr][1] = A.y; X[rr][2] = A.z; X[rr][3] = A.w;
                X[rr][4] = B.x; X[rr][5] = B.y; X[rr][6] = B.z; X[rr][7] = B.w;
                X[rr][8] = C.x; X[rr][9] = C.y; X[rr][10] = C.z; X[rr][11] = C.w;
            }
            #pragma unroll
            for (int rr = 0; rr < 3; ++rr)
                #pragma unroll
                for (int dx = 0; dx < 3; ++dx) {
                    float wv = w9[rr * 3 + dx];
                    #pragma unroll
                    for (int j = 0; j < 8; ++j) acc[j] += wv * X[rr][j + dx];
                }
        }
    }
    float bv = bias_f[co];
    long ob = ((long)(n * 256 + co)) * 4096 + r * 64 + px0 + pg * 8;
    #pragma unroll
    for (int j = 0; j < 8; ++j) out[ob + j] = __float2bfloat16(acc[j] + bv);
}

// ---------------- block reduction (up to 16 waves) -------------------------
__device__ __forceinline__ void reduce2(float& sum, float& sq, float* s1, float* s2)
{
    for (int off = 32; off; off >>= 1) {
        sum += __shfl_down(sum, off, 64);
        sq  += __shfl_down(sq,  off, 64);
    }
    int nw = blockDim.x >> 6;
    int wid = threadIdx.x >> 6;
    if ((threadIdx.x & 63) == 0) { s1[wid] = sum; s2[wid] = sq; }
    __syncthreads();
    sum = 0.f; sq = 0.f;
    for (int w = 0; w < nw; ++w) { sum += s1[w]; sq += s2[w]; }
}

// ---------------- instance norm (in place), optional relu ------------------
__global__ void instnorm_kernel(
    void* __restrict__ buf, long base0, int isWS, const int* __restrict__ dflag,
    int HW, int relu)
{
    __shared__ float s1[16], s2[16];
    int bf = isWS ? 1 : *dflag;
    long base = base0 + (long)blockIdx.x * HW;
    float sum = 0.f, sq = 0.f;
    for (int i = threadIdx.x; i < HW; i += blockDim.x) {
        float v = bf ? bitsToF(((const unsigned short*)buf)[base + i])
                     : ((const float*)buf)[base + i];
        sum += v; sq += v * v;
    }
    reduce2(sum, sq, s1, s2);
    float mean = sum / HW;
    float inv = rsqrtf(sq / HW - mean * mean + 1e-5f);
    for (int i = threadIdx.x; i < HW; i += blockDim.x) {
        float v = bf ? bitsToF(((const unsigned short*)buf)[base + i])
                     : ((const float*)buf)[base + i];
        v = (v - mean) * inv;
        if (relu) v = fmaxf(v, 0.f);
        if (bf) ((bf16*)buf)[base + i] = __float2bfloat16(v);
        else    ((float*)buf)[base + i] = v;
    }
}

// h += IN(t)   (bf16 ws chain, res-block 1 tail)
__global__ __launch_bounds__(TPB) void instnorm_add_kernel(
    const bf16* __restrict__ t, bf16* __restrict__ h, int HW)
{
    __shared__ float s1[16], s2[16];
    long base = (long)blockIdx.x * HW;
    const bf16* p = t + base;
    bf16* q = h + base;
    float sum = 0.f, sq = 0.f;
    for (int i = threadIdx.x; i < HW; i += TPB) { float v = toF(p[i]); sum += v; sq += v * v; }
    reduce2(sum, sq, s1, s2);
    float mean = sum / HW;
    float inv = rsqrtf(sq / HW - mean * mean + 1e-5f);
    for (int i = threadIdx.x; i < HW; i += TPB)
        q[i] = __float2bfloat16(toF(q[i]) + (toF(p[i]) - mean) * inv);
}

// out = h + IN(t)   (res-block 2 tail, writes d_out per flag)
__global__ __launch_bounds__(TPB) void instnorm_add_out_kernel(
    const bf16* __restrict__ t, const bf16* __restrict__ h,
    void* __restrict__ outp, const int* __restrict__ dflag, int HW)
{
    __shared__ float s1[16], s2[16];
    int bf = *dflag;
    long base = (long)blockIdx.x * HW;
    const bf16* p = t + base;
    const bf16* q = h + base;
    float sum = 0.f, sq = 0.f;
    for (int i = threadIdx.x; i < HW; i += TPB) { float v = toF(p[i]); sum += v; sq += v * v; }
    reduce2(sum, sq, s1, s2);
    float mean = sum / HW;
    float inv = rsqrtf(sq / HW - mean * mean + 1e-5f);
    for (int i = threadIdx.x; i < HW; i += TPB) {
        float v = toF(q[i]) + (toF(p[i]) - mean) * inv;
        if (bf) ((bf16*)outp)[base + i] = __float2bfloat16(v);
        else    ((float*)outp)[base + i] = v;
    }
}

// ---------------------------------------------------------------------------
extern "C" void kernel_launch(void* const* d_in, const int* in_sizes, int n_in,
                              void* d_out, int out_size, void* d_ws, size_t ws_size,
                              hipStream_t stream) {
    const void* x = d_in[0];

    const long SKIP1 = 2097152;
    const long SKIP2 = 10485760;

    int* dflag = (int*)d_ws;
    float* fw = (float*)((char*)d_ws + 64);

    bf16* t1 = (bf16*)(fw + FB);
    bf16* t2 = (bf16*)(fw + FB + 1048576);
    bf16* h3 = (bf16*)(fw + H3F);
    float* offb = fw + OFFB;

    detect_kernel<<<1, 64, 0, stream>>>(x, dflag);

    // ---- fused weight/bias repack (one launch) ----
    PtrPack pp;
    pp.p[0] = d_in[1];  pp.p[1] = d_in[3];  pp.p[2] = d_in[5];  pp.p[3] = d_in[7];
    pp.p[4] = d_in[9];  pp.p[5] = d_in[11]; pp.p[6] = d_in[13]; pp.p[7] = d_in[15];
    pp.p[8] = d_in[17]; pp.p[9] = d_in[19];
    pp.p[10] = d_in[2];  pp.p[11] = d_in[4];  pp.p[12] = d_in[6];  pp.p[13] = d_in[8];
    pp.p[14] = d_in[10]; pp.p[15] = d_in[12]; pp.p[16] = d_in[14]; pp.p[17] = d_in[16];
    pp.p[18] = d_in[18]; pp.p[19] = d_in[20];
    repack_all_kernel<<<3122, TPB, 0, stream>>>(pp, fw, dflag);

    // ---- Layer 1 fused: offsets + deform, 7x7 s1 p3 ----
    layer1_kernel<<<4096, TPB, 0, stream>>>(
        x, fw + OFF1T, fw + DCN1T, fw + OFF1B, fw + DCN1B, d_out, SKIP1, dflag);
    instnorm_kernel<<<128, 1024, 0, stream>>>(d_out, SKIP1, 0, dflag, 65536, 1);

    // ---- Layer 2: 4x4 s2 p1, Cin=64 ----
    offconv_kernel<64, 4, 4, 2, 1, 8, 48, 64><<<4096, TPB, 0, stream>>>(
        d_out, SKIP1, fw + OFF2T, fw + OFF2B, offb, dflag, 256, 256, 128, 128);
    deform_kernel<0, 64, 4, 4, 2, 1, 8, 128, 128><<<4096, TPB, 0, stream>>>(
        d_out, SKIP1, offb, fw + DCN2T, fw + DCN2B, d_out, SKIP2, dflag, 256, 256, 128, 128);
    instnorm_kernel<<<256, 512, 0, stream>>>(d_out, SKIP2, 0, dflag, 16384, 1);

    // ---- Layer 3: 4x4 s2 p1, Cin=128; output bf16 h3 ----
    offconv_kernel<128, 4, 4, 2, 1, 4, 48, 64><<<2048, TPB, 0, stream>>>(
        d_out, SKIP2, fw + OFF3T, fw + OFF3B, offb, dflag, 128, 128, 64, 64);
    deform_kernel<1, 128, 4, 4, 2, 1, 4, 256, 256><<<2048, TPB, 0, stream>>>(
        d_out, SKIP2, offb, fw + DCN3T, fw + DCN3B, h3, 0, dflag, 128, 128, 64, 64);
    instnorm_kernel<<<512, TPB, 0, stream>>>(h3, 0, 1, dflag, 4096, 1);

    // ---- Res block 1 ---- (wT_dcn/offb dead; t1/t2 live)
    resconv_kernel<<<1024, TPB, 0, stream>>>(h3, fw + RB1W1T, fw + RB1B1, t1);
    instnorm_kernel<<<512, TPB, 0, stream>>>(t1, 0, 1, dflag, 4096, 1);
    resconv_kernel<<<1024, TPB, 0, stream>>>(t1, fw + RB1W2T, fw + RB1B2, t2);
    instnorm_add_kernel<<<512, TPB, 0, stream>>>(t2, h3, 4096);

    // ---- Res block 2 (final IN+add writes d_out per flag) ----
    resconv_kernel<<<1024, TPB, 0, stream>>>(h3, fw + RB2W1T, fw + RB2B1, t1);
    instnorm_kernel<<<512, TPB, 0, stream>>>(t1, 0, 1, dflag, 4096, 1);
    resconv_kernel<<<1024, TPB, 0, stream>>>(t1, fw + RB2W2T, fw + RB2B2, t2);
    instnorm_add_out_kernel<<<512, TPB, 0, stream>>>(t2, h3, d_out, dflag, 4096);
}

// Round 10
// 1794.944 us; speedup vs baseline: 5.5990x; 1.1640x over previous
//
#include <hip/hip_runtime.h>
#include <hip/hip_bf16.h>
#include <math.h>

#define TPB 256
typedef __hip_bfloat16 bf16;
typedef short bf16x8 __attribute__((ext_vector_type(8)));   // 8 bf16 (4 VGPRs)
typedef float f32x4 __attribute__((ext_vector_type(4)));

// ---------------- ws layout constants (fp32-element offsets from fw) -------
constexpr long BIASF  = 0;          // 1715 packed fp32 biases (pad to 2048)
constexpr long RB1W1T = 2048;       // res weights now bf16 [9][256co][256ci]
constexpr long RB1W2T = 591872;     //   (each uses half its old fp32 region)
constexpr long RB2W1T = 1181696;
constexpr long RB2W2T = 1771520;
constexpr long FB     = 2361344;    // multi-use region
constexpr long OFF1T  = 2361344;
constexpr long DCN1T  = 2382953;
constexpr long OFF2T  = 2392361;
constexpr long DCN2T  = 2441513;
constexpr long OFF3T  = 2572585;
constexpr long DCN3T  = 2670889;    // ends 3195177
constexpr long OFFB   = 3221504;    // offsets during layers (dead at res time)
constexpr long H3F    = 4458496;    // h3 bf16 channels-last, 1048576 floats
constexpr long PSUM   = 5507072;    // IN partial sums [2][16][256]
constexpr long PSQ    = 5515264;    // IN partial sumsq
// bias sub-offsets
constexpr long OFF1B = 0,   DCN1B = 147;
constexpr long OFF2B = 211, DCN2B = 259;
constexpr long OFF3B = 387, DCN3B = 435;
constexpr long RB1B1 = 691, RB1B2 = 947;
constexpr long RB2B1 = 1203, RB2B2 = 1459;
// t1 = bf16[FB, FB+1048576 floats), t2 = bf16[FB+1048576, H3F) — all
// channels-last [n][64][64][256]. NO aliased partial buffers (R7/R8 lessons).

// ---- compile-time dtype accessors (BF=1: bf16, BF=0: fp32) ----------------
template<int BF>
__device__ __forceinline__ float ldT(const void* p, long i) {
    if (BF) {
        unsigned short h = ((const unsigned short*)p)[i];
        return __uint_as_float(((unsigned int)h) << 16);
    }
    return ((const float*)p)[i];
}
template<int BF>
__device__ __forceinline__ void stT(void* p, long i, float v) {
    if (BF) ((bf16*)p)[i] = __float2bfloat16(v);
    else    ((float*)p)[i] = v;
}
__device__ __forceinline__ float toF(bf16 v) { return __bfloat162float(v); }
__device__ __forceinline__ float bitsToF(unsigned short h) {
    return __uint_as_float(((unsigned int)h) << 16);
}
__device__ __forceinline__ unsigned short fToBits(float v) {
    bf16 h = __float2bfloat16(v);
    return *(unsigned short*)&h;
}

// ---- dtype detector (validated rounds 3-9) --------------------------------
__global__ void detect_kernel(const void* __restrict__ x, int* __restrict__ flag) {
    if (threadIdx.x == 0 && blockIdx.x == 0) {
        const unsigned short* u = (const unsigned short*)x;
        int sane = 0;
        for (int i = 0; i < 256; ++i) {
            float v = bitsToF(u[i]);
            float a = fabsf(v);
            if (a > 0.0009f && a < 1100.f) ++sane;
        }
        *flag = (sane >= 224) ? 1 : 0;
    }
}

// ===========================================================================
// Repack: non-res weights -> transposed fp32 wT[S][Cout]; biases -> fp32.
// ===========================================================================
struct PtrPack { const void* p[20]; };   // p[0..5]=non-res weights, p[10..19]=biases

template<int BF>
__device__ void repack_all_body(PtrPack pp, float* __restrict__ fw)
{
    constexpr int  bstart[7] = {0,22,32,80,208,304,816};
    constexpr int  sizes [6] = {21609,9408,49152,131072,98304,524288};
    constexpr int  coutA [6] = {147,64,48,128,48,256};
    constexpr int  sA    [6] = {147,147,1024,1024,2048,2048};
    constexpr long dstA  [6] = {OFF1T,DCN1T,OFF2T,DCN2T,OFF3T,DCN3T};
    constexpr int  bcum  [11] = {0,147,211,259,387,435,691,947,1203,1459,1715};

    int b = blockIdx.x;
    if (b < 816) {
        int seg = 0;
        #pragma unroll
        for (int s = 1; s < 6; ++s) if (b >= bstart[s]) seg = s;
        const void* src = pp.p[seg];
        float* dst = fw + dstA[seg];
        int Cout = coutA[seg], S = sA[seg], sz = sizes[seg];
        int idx0 = (b - bstart[seg]) * 1024 + threadIdx.x * 4;
        #pragma unroll
        for (int j = 0; j < 4; ++j) {
            int idx = idx0 + j;
            if (idx < sz) {
                int co = idx / S, i = idx - co * S;
                dst[(long)i * Cout + co] = ldT<BF>(src, idx);
            }
        }
    } else {
        int j0 = (b - 816) * 1024 + threadIdx.x * 4;
        #pragma unroll
        for (int q = 0; q < 4; ++q) {
            int j = j0 + q;
            if (j < 1715) {
                int v = 0;
                #pragma unroll
                for (int s = 1; s < 10; ++s) if (j >= bcum[s]) v = s;
                fw[BIASF + j] = ldT<BF>(pp.p[10 + v], j - bcum[v]);
            }
        }
    }
}
__global__ __launch_bounds__(TPB) void repack_all_kernel(
    PtrPack pp, float* fw, const int* dflag) {
    if (*dflag) repack_all_body<1>(pp, fw);
    else        repack_all_body<0>(pp, fw);
}

// ---- res weights: src[co][ci*9+q] (flag dtype) -> bf16 [q][co][ci] --------
struct RbPack { const void* src[4]; };
__global__ __launch_bounds__(TPB) void repack_rb_kernel(
    RbPack rp, float* fw, const int* dflag)
{
    __shared__ unsigned short lw[4 * 2304];
    int b = blockIdx.x;
    int ten = b >> 6;
    int co0 = (b & 63) * 4;
    const void* src = rp.src[ten];
    const long dstOff[4] = {RB1W1T, RB1W2T, RB2W1T, RB2W2T};
    unsigned short* dst = (unsigned short*)(fw + dstOff[ten]);
    int bf = *dflag;
    int t = threadIdx.x;
    for (int e = t; e < 4 * 2304; e += TPB) {
        int coL = e / 2304, i = e - coL * 2304;
        long si = (long)(co0 + coL) * 2304 + i;
        float v = bf ? ldT<1>(src, si) : ldT<0>(src, si);
        lw[e] = fToBits(v);
    }
    __syncthreads();
    for (int e = t; e < 9216; e += TPB) {     // 9216 = 9q * 4co * 256ci
        int ci = e & 255, coL = (e >> 8) & 3, q = e >> 10;
        dst[((long)q * 256 + co0 + coL) * 256 + ci] = lw[coL * 2304 + ci * 9 + q];
    }
}

// ===========================================================================
// Fused layer 1 (unchanged from round 9, validated)
// ===========================================================================
template<int BF>
__device__ void layer1_body(const void* __restrict__ x, const float* __restrict__ wt1,
                            const float* __restrict__ wt2, const float* __restrict__ bias1,
                            const float* __restrict__ bias2, void* __restrict__ out,
                            long obase, float* xs, float* offs, float* smp)
{
    int b = blockIdx.x;
    int n = b >> 11;
    int rt = b & 2047;
    int ho = rt >> 3;
    int wo0 = (rt & 7) << 5;
    long xn = (long)n * 3 * 65536;
    int t = threadIdx.x;

    for (int e = t; e < 3 * 7 * 40; e += TPB) {
        int cc = e % 40; int rr = (e / 40) % 7; int ci = e / 280;
        int yy = ho - 3 + rr; int xx = wo0 - 3 + cc;
        float v = 0.f;
        if (cc < 38 && yy >= 0 && yy < 256 && xx >= 0 && xx < 256)
            v = ldT<BF>(x, xn + (long)ci * 65536 + yy * 256 + xx);
        xs[e] = v;
    }
    __syncthreads();

    for (int e = t; e < 147 * 8; e += TPB) {
        int ch = e >> 3, pg = e & 7;
        int p0 = pg << 2;
        float bv = bias1[ch];
        float a0 = bv, a1 = bv, a2 = bv, a3 = bv;
        int i = 0;
        for (int ci = 0; ci < 3; ++ci)
            #pragma unroll
            for (int ky = 0; ky < 7; ++ky) {
                const float* xr = xs + (ci * 7 + ky) * 40 + p0;
                #pragma unroll
                for (int kx = 0; kx < 7; ++kx, ++i) {
                    float wv = wt1[i * 147 + ch];
                    a0 += wv * xr[kx];
                    a1 += wv * xr[kx + 1];
                    a2 += wv * xr[kx + 2];
                    a3 += wv * xr[kx + 3];
                }
            }
        float* orow = offs + ch * 32 + p0;
        orow[0] = a0; orow[1] = a1; orow[2] = a2; orow[3] = a3;
    }
    __syncthreads();

    for (int e = t; e < 147 * 32; e += TPB) {
        int p = e & 31; int rest = e >> 5;
        int k = rest % 49; int ci = rest / 49;
        float oy = offs[k * 32 + p];
        float ox = offs[(49 + k) * 32 + p];
        float mr = offs[(98 + k) * 32 + p];
        float m = 1.f / (1.f + expf(-mr));
        float py = (float)(ho - 3 + k / 7) + oy;
        float px = (float)(wo0 + p - 3 + k % 7) + ox;
        float y0f = floorf(py), x0f = floorf(px);
        float wy = py - y0f, wx = px - x0f;
        int y0 = (int)y0f, x0 = (int)x0f;
        bool yv0 = (y0 >= 0) && (y0 < 256);
        bool yv1 = (y0 + 1 >= 0) && (y0 + 1 < 256);
        bool xv0 = (x0 >= 0) && (x0 < 256);
        bool xv1 = (x0 + 1 >= 0) && (x0 + 1 < 256);
        int y0c = min(max(y0, 0), 255), y1c = min(max(y0 + 1, 0), 255);
        int x0c = min(max(x0, 0), 255), x1c = min(max(x0 + 1, 0), 255);
        long xc = xn + (long)ci * 65536;
        float v00 = (yv0 && xv0) ? ldT<BF>(x, xc + y0c * 256 + x0c) : 0.f;
        float v01 = (yv0 && xv1) ? ldT<BF>(x, xc + y0c * 256 + x1c) : 0.f;
        float v10 = (yv1 && xv0) ? ldT<BF>(x, xc + y1c * 256 + x0c) : 0.f;
        float v11 = (yv1 && xv1) ? ldT<BF>(x, xc + y1c * 256 + x1c) : 0.f;
        float val = ((1.f - wy) * ((1.f - wx) * v00 + wx * v01) +
                     wy * ((1.f - wx) * v10 + wx * v11)) * m;
        smp[e] = val;
    }
    __syncthreads();

    for (int e = t; e < 64 * 8; e += TPB) {
        int co = e >> 3, pg = e & 7;
        int p0 = pg << 2;
        float a0 = 0.f, a1 = 0.f, a2 = 0.f, a3 = 0.f;
        #pragma unroll 8
        for (int i = 0; i < 147; ++i) {
            float wv = wt2[i * 64 + co];
            const float4 v = *(const float4*)&smp[i * 32 + p0];
            a0 += wv * v.x; a1 += wv * v.y; a2 += wv * v.z; a3 += wv * v.w;
        }
        float bv = bias2[co];
        long ob = obase + ((long)(n * 64 + co) * 256 + ho) * 256 + wo0 + p0;
        stT<BF>(out, ob + 0, a0 + bv); stT<BF>(out, ob + 1, a1 + bv);
        stT<BF>(out, ob + 2, a2 + bv); stT<BF>(out, ob + 3, a3 + bv);
    }
}

__global__ __launch_bounds__(TPB) void layer1_kernel(
    const void* x, const float* wt1, const float* wt2,
    const float* bias1, const float* bias2, void* out, long obase, const int* dflag)
{
    __shared__ __align__(16) float xs[3 * 7 * 40];
    __shared__ __align__(16) float offs[147 * 32];
    __shared__ __align__(16) float smp[147 * 32];
    if (*dflag) layer1_body<1>(x, wt1, wt2, bias1, bias2, out, obase, xs, offs, smp);
    else        layer1_body<0>(x, wt1, wt2, bias1, bias2, out, obase, xs, offs, smp);
}

// ===========================================================================
// Offset conv for layers 2/3 (unchanged from round 9)
// ===========================================================================
template<int BF, int CIN, int KH, int KW, int ST, int PAD, int TPIX, int COUT, int COUTP>
__device__ void offconv_body(const void* __restrict__ x, long xbase,
                             const float* __restrict__ wt, const float* __restrict__ bias_f,
                             float* __restrict__ out, float* smp, int H, int W, int Ho, int Wo)
{
    constexpr int K = KH * KW, S = CIN * K;
    int tilesPerN = (Ho * Wo) / TPIX;
    int n = blockIdx.x / tilesPerN;
    int lp0 = (blockIdx.x % tilesPerN) * TPIX;
    long xn = xbase + (long)n * CIN * H * W;
    for (int e = threadIdx.x; e < S * TPIX; e += TPB) {
        int p = e % TPIX; int rest = e / TPIX;
        int k = rest % K; int ci = rest / K;
        int lp = lp0 + p;
        int ho = lp / Wo, wo = lp % Wo;
        int yy = ho * ST - PAD + k / KW;
        int xx = wo * ST - PAD + k % KW;
        float v = 0.f;
        if (yy >= 0 && yy < H && xx >= 0 && xx < W)
            v = ldT<BF>(x, xn + (long)ci * H * W + (long)yy * W + xx);
        smp[rest * TPIX + p] = v;
    }
    __syncthreads();
    constexpr int PXG = (TPIX * COUTP) / TPB;
    int co = threadIdx.x % COUTP;
    int g  = threadIdx.x / COUTP;
    if (co >= COUT) return;
    int pb = g * PXG;
    float acc[PXG];
    #pragma unroll
    for (int j = 0; j < PXG; ++j) acc[j] = 0.f;
    #pragma unroll 8
    for (int i = 0; i < S; ++i) {
        float wv = wt[(long)i * COUT + co];
        #pragma unroll
        for (int j = 0; j < PXG; ++j) acc[j] += wv * smp[i * TPIX + pb + j];
    }
    float bv = bias_f[co];
    int lp = lp0 + pb;
    int lr = lp / Wo, wo = lp % Wo;
    long ob = ((long)(n * COUT + co) * Ho + lr) * Wo + wo;
    #pragma unroll
    for (int j = 0; j < PXG; ++j) out[ob + j] = acc[j] + bv;
}

template<int CIN, int KH, int KW, int ST, int PAD, int TPIX, int COUT, int COUTP>
__global__ __launch_bounds__(TPB) void offconv_kernel(
    const void* x, long xbase, const float* wt, const float* bias_f, float* out,
    const int* dflag, int H, int W, int Ho, int Wo)
{
    __shared__ __align__(16) float smp[CIN * KH * KW * TPIX];
    if (*dflag)
        offconv_body<1, CIN, KH, KW, ST, PAD, TPIX, COUT, COUTP>(
            x, xbase, wt, bias_f, out, smp, H, W, Ho, Wo);
    else
        offconv_body<0, CIN, KH, KW, ST, PAD, TPIX, COUT, COUTP>(
            x, xbase, wt, bias_f, out, smp, H, W, Ho, Wo);
}

// ===========================================================================
// Deformable conv layers 2/3. CL=1 -> bf16 channels-last output [n][pos][co].
// ===========================================================================
template<int BF, int OBF, int CL, int CIN, int KH, int KW, int ST, int PAD, int TPIX, int COUT, int COUTP>
__device__ void deform_body(const void* __restrict__ x, long xbase,
                            const float* __restrict__ off, const float* __restrict__ wt,
                            const float* __restrict__ bias_f, void* __restrict__ out,
                            long obase, float* smp, int H, int W, int Ho, int Wo)
{
    constexpr int K = KH * KW, S = CIN * K;
    int tilesPerN = (Ho * Wo) / TPIX;
    int n = blockIdx.x / tilesPerN;
    int lp0 = (blockIdx.x % tilesPerN) * TPIX;
    long xn = xbase + (long)n * CIN * H * W;
    const float* offn = off + (long)n * 3 * K * Ho * Wo;
    long planeSz = (long)Ho * Wo;

    for (int e = threadIdx.x; e < S * TPIX; e += TPB) {
        int p = e % TPIX; int rest = e / TPIX;
        int k = rest % K; int ci = rest / K;
        int lp = lp0 + p;
        int ho = lp / Wo, wo = lp % Wo;
        float oy = offn[(long)k * planeSz + lp];
        float ox = offn[(long)(K + k) * planeSz + lp];
        float mr = offn[(long)(2 * K + k) * planeSz + lp];
        float m = 1.f / (1.f + expf(-mr));
        float py = (float)(ho * ST - PAD + (k / KW)) + oy;
        float px = (float)(wo * ST - PAD + (k % KW)) + ox;
        float y0f = floorf(py), x0f = floorf(px);
        float wy = py - y0f, wx = px - x0f;
        int y0 = (int)y0f, x0 = (int)x0f;
        bool yv0 = (y0 >= 0) && (y0 < H);
        bool yv1 = (y0 + 1 >= 0) && (y0 + 1 < H);
        bool xv0 = (x0 >= 0) && (x0 < W);
        bool xv1 = (x0 + 1 >= 0) && (x0 + 1 < W);
        int y0c = min(max(y0, 0), H - 1), y1c = min(max(y0 + 1, 0), H - 1);
        int x0c = min(max(x0, 0), W - 1), x1c = min(max(x0 + 1, 0), W - 1);
        long xc = xn + (long)ci * H * W;
        float v00 = (yv0 && xv0) ? ldT<BF>(x, xc + (long)y0c * W + x0c) : 0.f;
        float v01 = (yv0 && xv1) ? ldT<BF>(x, xc + (long)y0c * W + x1c) : 0.f;
        float v10 = (yv1 && xv0) ? ldT<BF>(x, xc + (long)y1c * W + x0c) : 0.f;
        float v11 = (yv1 && xv1) ? ldT<BF>(x, xc + (long)y1c * W + x1c) : 0.f;
        float val = ((1.f - wy) * ((1.f - wx) * v00 + wx * v01) +
                     wy * ((1.f - wx) * v10 + wx * v11)) * m;
        smp[rest * TPIX + p] = val;
    }
    __syncthreads();

    constexpr int PXG = (TPIX * COUTP) / TPB;
    static_assert(PXG == 4, "deform GEMM assumes PXG==4");
    int co = threadIdx.x % COUTP;
    int g  = threadIdx.x / COUTP;
    int pb = g * PXG;
    float a0 = 0.f, a1 = 0.f, a2 = 0.f, a3 = 0.f;
    #pragma unroll 8
    for (int i = 0; i < S; ++i) {
        float wv = wt[(long)i * COUT + co];
        const float4 v = *(const float4*)&smp[i * TPIX + pb];
        a0 += wv * v.x; a1 += wv * v.y; a2 += wv * v.z; a3 += wv * v.w;
    }
    float bv = bias_f[co];
    if (CL) {
        long pos = (long)n * planeSz + lp0 + pb;
        stT<1>(out, (pos + 0) * COUT + co, a0 + bv);
        stT<1>(out, (pos + 1) * COUT + co, a1 + bv);
        stT<1>(out, (pos + 2) * COUT + co, a2 + bv);
        stT<1>(out, (pos + 3) * COUT + co, a3 + bv);
    } else {
        int lp = lp0 + pb;
        int lr = lp / Wo, wo = lp % Wo;
        long ob = obase + ((long)(n * COUT + co) * Ho + lr) * Wo + wo;
        stT<OBF>(out, ob + 0, a0 + bv); stT<OBF>(out, ob + 1, a1 + bv);
        stT<OBF>(out, ob + 2, a2 + bv); stT<OBF>(out, ob + 3, a3 + bv);
    }
}

template<int OUTMODE, int CIN, int KH, int KW, int ST, int PAD, int TPIX, int COUT, int COUTP>
__global__ __launch_bounds__(TPB) void deform_kernel(
    const void* x, long xbase, const float* off, const float* wt, const float* bias_f,
    void* out, long obase, const int* dflag, int H, int W, int Ho, int Wo)
{
    __shared__ __align__(16) float smp[CIN * KH * KW * TPIX];
    if (*dflag)
        deform_body<1, 1, (OUTMODE == 2), CIN, KH, KW, ST, PAD, TPIX, COUT, COUTP>(
            x, xbase, off, wt, bias_f, out, obase, smp, H, W, Ho, Wo);
    else
        deform_body<0, (OUTMODE ? 1 : 0), (OUTMODE == 2), CIN, KH, KW, ST, PAD, TPIX, COUT, COUTP>(
            x, xbase, off, wt, bias_f, out, obase, smp, H, W, Ho, Wo);
}

// ===========================================================================
// MFMA res-block 3x3 reflect conv. X,Y bf16 channels-last [n][64][64][256].
// W bf16 [q][co][ci]. Implicit GEMM: M=px(16/wave), N=co(64/wave), K=ci.
// 9 shifted GEMMs (q = ky*3+kx). Block=(n, row, coQuarter), grid 512.
// Layouts (learn_hip-verified): A[m=lane&15][k=quad*8+j] (m120);
// C/D col=lane&15(=n), row=quad*4+reg(=m) (m89). B by symmetry.
// ===========================================================================
__global__ __launch_bounds__(TPB) void resconv_mfma_kernel(
    const unsigned short* __restrict__ X, const unsigned short* __restrict__ W,
    const float* __restrict__ bias_f, bf16* __restrict__ Y)
{
    __shared__ __align__(16) unsigned short xs[3 * 66 * 32];
    int b = blockIdx.x;
    int coQ = b & 3, r = (b >> 2) & 63, n = b >> 8;
    int t = threadIdx.x;
    int wv = t >> 6;
    int lane = t & 63;
    int quad = lane >> 4, l16 = lane & 15;
    int rows[3];
    rows[0] = (r == 0) ? 1 : r - 1;
    rows[1] = r;
    rows[2] = (r == 63) ? 62 : r + 1;

    f32x4 acc[4];
    #pragma unroll
    for (int ct = 0; ct < 4; ++ct) acc[ct] = (f32x4){0.f, 0.f, 0.f, 0.f};

    long xbase = (long)n * 4096 * 256;

    for (int ci0 = 0; ci0 < 256; ci0 += 32) {
        __syncthreads();
        // stage X[3 rows][cols -1..64][32 ci] (reflect), ci contiguous
        for (int e = t; e < 3 * 66 * 32; e += TPB) {
            int ci = e & 31;
            int col = (e >> 5) % 66;
            int ky = e / 2112;
            int gx = col - 1;
            gx = (gx < 0) ? 1 : ((gx > 63) ? 62 : gx);
            xs[e] = X[xbase + ((long)rows[ky] * 64 + gx) * 256 + ci0 + ci];
        }
        __syncthreads();
        #pragma unroll
        for (int q = 0; q < 9; ++q) {
            int ky = q / 3, kx = q % 3;
            int colIdx = wv * 16 + l16 + kx;        // lds col = global col +1
            bf16x8 a = *(const bf16x8*)&xs[(ky * 66 + colIdx) * 32 + quad * 8];
            #pragma unroll
            for (int ct = 0; ct < 4; ++ct) {
                int co = coQ * 64 + ct * 16 + l16;
                bf16x8 bw = *(const bf16x8*)&W[((long)q * 256 + co) * 256 + ci0 + quad * 8];
                acc[ct] = __builtin_amdgcn_mfma_f32_16x16x32_bf16(a, bw, acc[ct], 0, 0, 0);
            }
        }
    }

    long ybase = ((long)n * 4096 + (long)r * 64) * 256;
    #pragma unroll
    for (int ct = 0; ct < 4; ++ct) {
        int co = coQ * 64 + ct * 16 + l16;
        float bv = bias_f[co];
        #pragma unroll
        for (int reg = 0; reg < 4; ++reg) {
            int px = wv * 16 + quad * 4 + reg;
            Y[ybase + (long)px * 256 + co] = __float2bfloat16(acc[ct][reg] + bv);
        }
    }
}

// ===========================================================================
// Channels-last instance-norm: partial stats + apply kernels
// ===========================================================================
// grid 32 = n*16 + chunk(256 positions); thread = channel
__global__ __launch_bounds__(TPB) void cl_stats_kernel(
    const unsigned short* __restrict__ X, float* __restrict__ psum, float* __restrict__ psq)
{
    int blk = blockIdx.x;
    int chunk = blk & 15, n = blk >> 4;
    int co = threadIdx.x;
    float s = 0.f, sq = 0.f;
    const unsigned short* p = X + ((long)n * 4096 + chunk * 256) * 256 + co;
    for (int i = 0; i < 256; ++i) {
        float v = bitsToF(p[(long)i * 256]);
        s += v; sq += v * v;
    }
    psum[(n * 16 + chunk) * 256 + co] = s;
    psq [(n * 16 + chunk) * 256 + co] = sq;
}

__device__ __forceinline__ void cl_load_stats(
    const float* psum, const float* psq, int n, float* mv, float* iv)
{
    int t = threadIdx.x;   // t = channel
    float s = 0.f, sq = 0.f;
    for (int c = 0; c < 16; ++c) {
        s  += psum[(n * 16 + c) * 256 + t];
        sq += psq [(n * 16 + c) * 256 + t];
    }
    float mean = s / 4096.f;
    mv[t] = mean;
    iv[t] = rsqrtf(sq / 4096.f - mean * mean + 1e-5f);
    __syncthreads();
}

// grid 128 = n*64 + y; in-place X = relu?((X-m)*inv)
__global__ __launch_bounds__(TPB) void cl_apply_kernel(
    unsigned short* __restrict__ X, const float* __restrict__ psum,
    const float* __restrict__ psq, int relu)
{
    __shared__ float mv[256], iv[256];
    int y = blockIdx.x & 63, n = blockIdx.x >> 6;
    cl_load_stats(psum, psq, n, mv, iv);
    unsigned short* row = X + ((long)n * 4096 + y * 64) * 256;
    for (int e = threadIdx.x; e < 64 * 256; e += TPB) {
        int co = e & 255;
        float v = (bitsToF(row[e]) - mv[co]) * iv[co];
        if (relu) v = fmaxf(v, 0.f);
        row[e] = fToBits(v);
    }
}

// grid 128; H += IN(T)
__global__ __launch_bounds__(TPB) void cl_apply_add_kernel(
    const unsigned short* __restrict__ T, unsigned short* __restrict__ H,
    const float* __restrict__ psum, const float* __restrict__ psq)
{
    __shared__ float mv[256], iv[256];
    int y = blockIdx.x & 63, n = blockIdx.x >> 6;
    cl_load_stats(psum, psq, n, mv, iv);
    long base = ((long)n * 4096 + y * 64) * 256;
    for (int e = threadIdx.x; e < 64 * 256; e += TPB) {
        int co = e & 255;
        float v = bitsToF(H[base + e]) + (bitsToF(T[base + e]) - mv[co]) * iv[co];
        H[base + e] = fToBits(v);
    }
}

// grid 128; out(NCHW, flag dtype) = H + IN(T)   (transposes channels-last)
__global__ __launch_bounds__(TPB) void cl_apply_final_kernel(
    const unsigned short* __restrict__ T, const unsigned short* __restrict__ H,
    void* __restrict__ outp, const float* __restrict__ psum,
    const float* __restrict__ psq, const int* __restrict__ dflag)
{
    __shared__ float mv[256], iv[256];
    int y = blockIdx.x & 63, n = blockIdx.x >> 6;
    cl_load_stats(psum, psq, n, mv, iv);
    int bf = *dflag;
    int x = threadIdx.x & 63, cg = threadIdx.x >> 6;
    for (int co = cg; co < 256; co += 4) {
        long cli = ((long)(n * 64 + y) * 64 + x) * 256 + co;
        float v = bitsToF(H[cli]) + (bitsToF(T[cli]) - mv[co]) * iv[co];
        long oi = (((long)(n * 256 + co)) * 64 + y) * 64 + x;
        if (bf) ((bf16*)outp)[oi] = __float2bfloat16(v);
        else    ((float*)outp)[oi] = v;
    }
}

// ---------------- block reduction (up to 16 waves) -------------------------
__device__ __forceinline__ void reduce2(float& sum, float& sq, float* s1, float* s2)
{
    for (int off = 32; off; off >>= 1) {
        sum += __shfl_down(sum, off, 64);
        sq  += __shfl_down(sq,  off, 64);
    }
    int nw = blockDim.x >> 6;
    int wid = threadIdx.x >> 6;
    if ((threadIdx.x & 63) == 0) { s1[wid] = sum; s2[wid] = sq; }
    __syncthreads();
    sum = 0.f; sq = 0.f;
    for (int w = 0; w < nw; ++w) { sum += s1[w]; sq += s2[w]; }
}

// ---------------- instance norm for skip1/skip2 (d_out, flag dtype) --------
__global__ void instnorm_kernel(
    void* __restrict__ buf, long base0, const int* __restrict__ dflag,
    int HW, int relu)
{
    __shared__ float s1[16], s2[16];
    int bf = *dflag;
    long base = base0 + (long)blockIdx.x * HW;
    float sum = 0.f, sq = 0.f;
    for (int i = threadIdx.x; i < HW; i += blockDim.x) {
        float v = bf ? bitsToF(((const unsigned short*)buf)[base + i])
                     : ((const float*)buf)[base + i];
        sum += v; sq += v * v;
    }
    reduce2(sum, sq, s1, s2);
    float mean = sum / HW;
    float inv = rsqrtf(sq / HW - mean * mean + 1e-5f);
    for (int i = threadIdx.x; i < HW; i += blockDim.x) {
        float v = bf ? bitsToF(((const unsigned short*)buf)[base + i])
                     : ((const float*)buf)[base + i];
        v = (v - mean) * inv;
        if (relu) v = fmaxf(v, 0.f);
        if (bf) ((bf16*)buf)[base + i] = __float2bfloat16(v);
        else    ((float*)buf)[base + i] = v;
    }
}

// ---------------------------------------------------------------------------
extern "C" void kernel_launch(void* const* d_in, const int* in_sizes, int n_in,
                              void* d_out, int out_size, void* d_ws, size_t ws_size,
                              hipStream_t stream) {
    const void* x = d_in[0];

    const long SKIP1 = 2097152;
    const long SKIP2 = 10485760;

    int* dflag = (int*)d_ws;
    float* fw = (float*)((char*)d_ws + 64);

    unsigned short* t1 = (unsigned short*)(fw + FB);
    unsigned short* t2 = (unsigned short*)(fw + FB + 1048576);
    unsigned short* h3 = (unsigned short*)(fw + H3F);
    float* offb = fw + OFFB;
    float* psum = fw + PSUM;
    float* psq  = fw + PSQ;
    const unsigned short* rbw1 = (const unsigned short*)(fw + RB1W1T);
    const unsigned short* rbw2 = (const unsigned short*)(fw + RB1W2T);
    const unsigned short* rbw3 = (const unsigned short*)(fw + RB2W1T);
    const unsigned short* rbw4 = (const unsigned short*)(fw + RB2W2T);

    detect_kernel<<<1, 64, 0, stream>>>(x, dflag);

    // ---- weight/bias repack ----
    PtrPack pp;
    pp.p[0] = d_in[1];  pp.p[1] = d_in[3];  pp.p[2] = d_in[5];
    pp.p[3] = d_in[7];  pp.p[4] = d_in[9];  pp.p[5] = d_in[11];
    pp.p[6] = pp.p[7] = pp.p[8] = pp.p[9] = nullptr;
    pp.p[10] = d_in[2];  pp.p[11] = d_in[4];  pp.p[12] = d_in[6];  pp.p[13] = d_in[8];
    pp.p[14] = d_in[10]; pp.p[15] = d_in[12]; pp.p[16] = d_in[14]; pp.p[17] = d_in[16];
    pp.p[18] = d_in[18]; pp.p[19] = d_in[20];
    repack_all_kernel<<<818, TPB, 0, stream>>>(pp, fw, dflag);
    RbPack rp;
    rp.src[0] = d_in[13]; rp.src[1] = d_in[15]; rp.src[2] = d_in[17]; rp.src[3] = d_in[19];
    repack_rb_kernel<<<256, TPB, 0, stream>>>(rp, fw, dflag);

    // ---- Layer 1 fused: offsets + deform, 7x7 s1 p3 ----
    layer1_kernel<<<4096, TPB, 0, stream>>>(
        x, fw + OFF1T, fw + DCN1T, fw + OFF1B, fw + DCN1B, d_out, SKIP1, dflag);
    instnorm_kernel<<<128, 1024, 0, stream>>>(d_out, SKIP1, dflag, 65536, 1);

    // ---- Layer 2: 4x4 s2 p1, Cin=64 ----
    offconv_kernel<64, 4, 4, 2, 1, 8, 48, 64><<<4096, TPB, 0, stream>>>(
        d_out, SKIP1, fw + OFF2T, fw + OFF2B, offb, dflag, 256, 256, 128, 128);
    deform_kernel<0, 64, 4, 4, 2, 1, 8, 128, 128><<<4096, TPB, 0, stream>>>(
        d_out, SKIP1, offb, fw + DCN2T, fw + DCN2B, d_out, SKIP2, dflag, 256, 256, 128, 128);
    instnorm_kernel<<<256, 512, 0, stream>>>(d_out, SKIP2, dflag, 16384, 1);

    // ---- Layer 3: 4x4 s2 p1, Cin=128; output bf16 channels-last h3 ----
    offconv_kernel<128, 4, 4, 2, 1, 4, 48, 64><<<2048, TPB, 0, stream>>>(
        d_out, SKIP2, fw + OFF3T, fw + OFF3B, offb, dflag, 128, 128, 64, 64);
    deform_kernel<2, 128, 4, 4, 2, 1, 4, 256, 256><<<2048, TPB, 0, stream>>>(
        d_out, SKIP2, offb, fw + DCN3T, fw + DCN3B, h3, 0, dflag, 128, 128, 64, 64);
    cl_stats_kernel<<<32, TPB, 0, stream>>>(h3, psum, psq);
    cl_apply_kernel<<<128, TPB, 0, stream>>>(h3, psum, psq, 1);

    // ---- Res block 1 (MFMA) ----
    resconv_mfma_kernel<<<512, TPB, 0, stream>>>(h3, rbw1, fw + RB1B1, (bf16*)t1);
    cl_stats_kernel<<<32, TPB, 0, stream>>>(t1, psum, psq);
    cl_apply_kernel<<<128, TPB, 0, stream>>>(t1, psum, psq, 1);
    resconv_mfma_kernel<<<512, TPB, 0, stream>>>(t1, rbw2, fw + RB1B2, (bf16*)t2);
    cl_stats_kernel<<<32, TPB, 0, stream>>>(t2, psum, psq);
    cl_apply_add_kernel<<<128, TPB, 0, stream>>>(t2, h3, psum, psq);

    // ---- Res block 2 (MFMA; final writes NCHW d_out per flag) ----
    resconv_mfma_kernel<<<512, TPB, 0, stream>>>(h3, rbw3, fw + RB2B1, (bf16*)t1);
    cl_stats_kernel<<<32, TPB, 0, stream>>>(t1, psum, psq);
    cl_apply_kernel<<<128, TPB, 0, stream>>>(t1, psum, psq, 1);
    resconv_mfma_kernel<<<512, TPB, 0, stream>>>(t1, rbw4, fw + RB2B2, (bf16*)t2);
    cl_stats_kernel<<<32, TPB, 0, stream>>>(t2, psum, psq);
    cl_apply_final_kernel<<<128, TPB, 0, stream>>>(t2, h3, d_out, psum, psq, dflag);
}